// Round 1
// baseline (689.314 us; speedup 1.0000x reference)
//
#include <hip/hip_runtime.h>

#define HIDDEN 2560
#define NHEADS 32
#define HDIM 80
#define DPAD 96
#define SEQ 2048
#define M_TOK 4096
#define N_QKV 7680
#define ATT_SCALE 0.11180339887498949f  // 80^-0.5

typedef __attribute__((ext_vector_type(4))) float f32x4;
typedef __attribute__((ext_vector_type(8))) short bf16x8;
typedef __attribute__((ext_vector_type(8))) unsigned short ushort8;

__device__ __forceinline__ unsigned short f2bf(float f) {
    unsigned int u = __float_as_uint(f);
    u += 0x7FFFu + ((u >> 16) & 1u);
    return (unsigned short)(u >> 16);
}
__device__ __forceinline__ float bf2f(unsigned short h) {
    return __uint_as_float(((unsigned int)h) << 16);
}

// ---------------- fp32 -> bf16 convert (8 elems/thread) ----------------
__global__ __launch_bounds__(256) void cvt_kernel(const float* __restrict__ in,
                                                  unsigned short* __restrict__ out, int n8) {
    int i = blockIdx.x * 256 + threadIdx.x;
    if (i >= n8) return;
    const float4* p = (const float4*)in + (size_t)i * 2;
    float4 a = p[0], b = p[1];
    ushort8 o;
    o[0] = f2bf(a.x); o[1] = f2bf(a.y); o[2] = f2bf(a.z); o[3] = f2bf(a.w);
    o[4] = f2bf(b.x); o[5] = f2bf(b.y); o[6] = f2bf(b.z); o[7] = f2bf(b.w);
    *((ushort8*)out + i) = o;
}

// ---------------- fp32 [R][C] -> bf16 [C][R] transpose ----------------
__global__ __launch_bounds__(256) void transpose_kernel(const float* __restrict__ in,
                                                        unsigned short* __restrict__ out,
                                                        int R, int C) {
    __shared__ unsigned short tile[64][66];
    const int r0 = blockIdx.y * 64, c0 = blockIdx.x * 64;
    const int t = threadIdx.x;
#pragma unroll
    for (int rep = 0; rep < 16; ++rep) {
        int idx = rep * 256 + t;
        int i = idx >> 6, j = idx & 63;
        tile[i][j] = f2bf(in[(size_t)(r0 + i) * C + (c0 + j)]);
    }
    __syncthreads();
#pragma unroll
    for (int rep = 0; rep < 16; ++rep) {
        int idx = rep * 256 + t;
        int j = idx >> 6, i = idx & 63;
        out[(size_t)(c0 + j) * R + (r0 + i)] = tile[i][j];
    }
}

// ---------------- bf16 GEMM: C[M][N] = A[M][K] * Bt[N][K]^T + bias ----------------
// 128x128 tile, BK=32, 256 threads (4 waves, 2x2), mfma 16x16x32 bf16.
template <int OUT_BF16>
__global__ __launch_bounds__(256) void gemm_bt(const unsigned short* __restrict__ A,
                                               const unsigned short* __restrict__ Bt,
                                               const float* __restrict__ bias,
                                               void* __restrict__ C, int M, int N, int K) {
    __shared__ __align__(16) unsigned short Alds[128 * 32];
    __shared__ __align__(16) unsigned short Blds[128 * 32];
    const int t = threadIdx.x;
    const int lane = t & 63, wid = t >> 6;
    const int wm = wid >> 1, wn = wid & 1;
    const int l15 = lane & 15, lhi = lane >> 4;
    const int bm = blockIdx.y * 128, bn = blockIdx.x * 128;

    f32x4 acc[4][4] = {};

    const int q1 = t, q2 = t + 256;
    const unsigned short* Aptr1 = A + (size_t)(bm + (q1 >> 2)) * K + (q1 & 3) * 8;
    const unsigned short* Aptr2 = A + (size_t)(bm + (q2 >> 2)) * K + (q2 & 3) * 8;
    const unsigned short* Bptr1 = Bt + (size_t)(bn + (q1 >> 2)) * K + (q1 & 3) * 8;
    const unsigned short* Bptr2 = Bt + (size_t)(bn + (q2 >> 2)) * K + (q2 & 3) * 8;

    const int aoff0 = (wm * 64 + l15) * 32 + lhi * 8;
    const int boff0 = (wn * 64 + l15) * 32 + lhi * 8;

    for (int k0 = 0; k0 < K; k0 += 32) {
        ushort8 ra1 = *(const ushort8*)(Aptr1 + k0);
        ushort8 ra2 = *(const ushort8*)(Aptr2 + k0);
        ushort8 rb1 = *(const ushort8*)(Bptr1 + k0);
        ushort8 rb2 = *(const ushort8*)(Bptr2 + k0);
        __syncthreads();
        *(ushort8*)(Alds + q1 * 8) = ra1;
        *(ushort8*)(Alds + q2 * 8) = ra2;
        *(ushort8*)(Blds + q1 * 8) = rb1;
        *(ushort8*)(Blds + q2 * 8) = rb2;
        __syncthreads();
        bf16x8 af[4], bfv[4];
#pragma unroll
        for (int i = 0; i < 4; i++) af[i] = *(const bf16x8*)(Alds + aoff0 + i * 16 * 32);
#pragma unroll
        for (int j = 0; j < 4; j++) bfv[j] = *(const bf16x8*)(Blds + boff0 + j * 16 * 32);
#pragma unroll
        for (int i = 0; i < 4; i++)
#pragma unroll
            for (int j = 0; j < 4; j++)
                acc[i][j] = __builtin_amdgcn_mfma_f32_16x16x32_bf16(af[i], bfv[j], acc[i][j], 0, 0, 0);
    }

#pragma unroll
    for (int j = 0; j < 4; j++) {
        const int col = bn + wn * 64 + j * 16 + l15;
        const float bv = bias[col];
#pragma unroll
        for (int i = 0; i < 4; i++) {
            const int row0 = bm + wm * 64 + i * 16 + lhi * 4;
#pragma unroll
            for (int r = 0; r < 4; r++) {
                float v = acc[i][j][r] + bv;
                if (OUT_BF16)
                    ((unsigned short*)C)[(size_t)(row0 + r) * N + col] = f2bf(v);
                else
                    ((float*)C)[(size_t)(row0 + r) * N + col] = v;
            }
        }
    }
}

// ---------------- pack qkv -> Q,K (rope, pad to 96), Vt (transposed) ----------------
__global__ __launch_bounds__(256) void pack_rope_kernel(const unsigned short* __restrict__ qkv,
                                                        const int* __restrict__ pos_ids,
                                                        unsigned short* __restrict__ Qb,
                                                        unsigned short* __restrict__ Kb,
                                                        unsigned short* __restrict__ Vt) {
    int g = blockIdx.x * 256 + threadIdx.x;  // (b*32+h)*2048 + s
    int s = g & (SEQ - 1);
    int bh = g >> 11;
    int b = bh >> 5;
    int h = bh & 31;
    int m = b * SEQ + s;
    const unsigned short* base = qkv + (size_t)m * N_QKV + h * HDIM;
    unsigned short* Qrow = Qb + ((size_t)bh * SEQ + s) * DPAD;
    unsigned short* Krow = Kb + ((size_t)bh * SEQ + s) * DPAD;
    unsigned short* Vcol = Vt + (size_t)bh * HDIM * SEQ + s;

    float pos = (float)pos_ids[m];
    float qv[32], kv[32];
#pragma unroll
    for (int c = 0; c < 4; ++c) {
        ushort8 qc = *(const ushort8*)(base + c * 8);
        ushort8 kc = *(const ushort8*)(base + HIDDEN + c * 8);
#pragma unroll
        for (int j = 0; j < 8; ++j) {
            qv[c * 8 + j] = bf2f(qc[j]);
            kv[c * 8 + j] = bf2f(kc[j]);
        }
    }
#pragma unroll
    for (int d = 0; d < 16; ++d) {
        float inv = __expf(-(float)d * 0.5756462732485115f);  // ln(10000)/16
        float ang = pos * inv;
        float sn, cs;
        __sincosf(ang, &sn, &cs);
        float x1 = qv[d], x2 = qv[d + 16];
        qv[d] = x1 * cs - x2 * sn;
        qv[d + 16] = x2 * cs + x1 * sn;
        x1 = kv[d]; x2 = kv[d + 16];
        kv[d] = x1 * cs - x2 * sn;
        kv[d + 16] = x2 * cs + x1 * sn;
    }
#pragma unroll
    for (int c = 0; c < 4; ++c) {
        ushort8 qo, ko;
#pragma unroll
        for (int j = 0; j < 8; ++j) {
            qo[j] = f2bf(qv[c * 8 + j]);
            ko[j] = f2bf(kv[c * 8 + j]);
        }
        *(ushort8*)(Qrow + c * 8) = qo;
        *(ushort8*)(Krow + c * 8) = ko;
    }
#pragma unroll
    for (int c = 4; c < 10; ++c) {
        *(ushort8*)(Qrow + c * 8) = *(const ushort8*)(base + c * 8);
        *(ushort8*)(Krow + c * 8) = *(const ushort8*)(base + HIDDEN + c * 8);
    }
    ushort8 z = {0, 0, 0, 0, 0, 0, 0, 0};
    *(ushort8*)(Qrow + 80) = z;
    *(ushort8*)(Qrow + 88) = z;
    *(ushort8*)(Krow + 80) = z;
    *(ushort8*)(Krow + 88) = z;
#pragma unroll
    for (int d = 0; d < HDIM; ++d) Vcol[(size_t)d * SEQ] = base[2 * HIDDEN + d];
}

// ---------------- causal flash attention ----------------
// grid: (S/64, B*H). 4 waves x 16 q-rows. K-tile 64. D padded 96 for QK^T, 80 for PV.
__global__ __launch_bounds__(256) void flash_kernel(const unsigned short* __restrict__ Qb,
                                                    const unsigned short* __restrict__ Kb,
                                                    const unsigned short* __restrict__ Vt,
                                                    unsigned short* __restrict__ attn) {
    __shared__ __align__(16) unsigned short Klds[64 * 96];
    __shared__ __align__(16) unsigned short Vlds[80 * 64];
    __shared__ __align__(16) unsigned short Plds[4 * 16 * 64];

    const int bh = blockIdx.y;
    const int q0 = blockIdx.x * 64;
    const int t = threadIdx.x, lane = t & 63, wid = t >> 6;
    const int l15 = lane & 15, lhi = lane >> 4;

    const unsigned short* Qrow = Qb + ((size_t)bh * SEQ + q0 + wid * 16 + l15) * DPAD + lhi * 8;
    bf16x8 qf[3];
#pragma unroll
    for (int kk = 0; kk < 3; kk++) qf[kk] = *(const bf16x8*)(Qrow + kk * 32);

    f32x4 acc_o[5] = {};
    float mrow[4] = {-1e30f, -1e30f, -1e30f, -1e30f};
    float lrow[4] = {0.f, 0.f, 0.f, 0.f};

    const int nkt = blockIdx.x + 1;
    const unsigned short* Kbase = Kb + (size_t)bh * SEQ * DPAD;
    const unsigned short* Vbase = Vt + (size_t)bh * HDIM * SEQ;

    for (int kt = 0; kt < nkt; ++kt) {
        const int k0 = kt * 64;
        __syncthreads();
#pragma unroll
        for (int c = 0; c < 3; ++c) {  // K tile [64][96]
            int q = t + c * 256;
            int row = q / 12, col = (q % 12) * 8;
            *(ushort8*)(Klds + q * 8) = *(const ushort8*)(Kbase + (size_t)(k0 + row) * DPAD + col);
        }
#pragma unroll
        for (int c = 0; c < 2; ++c) {  // Vt tile [80][64]
            int q = t + c * 256;
            int d = q >> 3, sc = (q & 7) * 8;
            *(ushort8*)(Vlds + q * 8) = *(const ushort8*)(Vbase + (size_t)d * SEQ + k0 + sc);
        }
        if (t < 128) {
            int q = 512 + t;
            int d = q >> 3, sc = (q & 7) * 8;
            *(ushort8*)(Vlds + q * 8) = *(const ushort8*)(Vbase + (size_t)d * SEQ + k0 + sc);
        }
        __syncthreads();

        f32x4 s4[4] = {};
#pragma unroll
        for (int ni = 0; ni < 4; ni++)
#pragma unroll
            for (int kk = 0; kk < 3; kk++) {
                bf16x8 bk = *(const bf16x8*)(Klds + (ni * 16 + l15) * 96 + kk * 32 + lhi * 8);
                s4[ni] = __builtin_amdgcn_mfma_f32_16x16x32_bf16(qf[kk], bk, s4[ni], 0, 0, 0);
            }

        const int rowg = q0 + wid * 16 + lhi * 4;
        float pmax[4] = {-1e30f, -1e30f, -1e30f, -1e30f};
#pragma unroll
        for (int ni = 0; ni < 4; ni++) {
            const int colg = k0 + ni * 16 + l15;
#pragma unroll
            for (int r = 0; r < 4; r++) {
                float v = s4[ni][r] * ATT_SCALE;
                v = (colg <= rowg + r) ? v : -1e30f;
                s4[ni][r] = v;
                pmax[r] = fmaxf(pmax[r], v);
            }
        }
#pragma unroll
        for (int off = 1; off < 16; off <<= 1)
#pragma unroll
            for (int r = 0; r < 4; r++) pmax[r] = fmaxf(pmax[r], __shfl_xor(pmax[r], off, 64));

        float scl[4], psum[4];
#pragma unroll
        for (int r = 0; r < 4; r++) {
            float mnew = fmaxf(mrow[r], pmax[r]);
            scl[r] = __expf(mrow[r] - mnew);
            mrow[r] = mnew;
            psum[r] = 0.f;
        }
#pragma unroll
        for (int ni = 0; ni < 4; ni++)
#pragma unroll
            for (int r = 0; r < 4; r++) {
                float p = __expf(s4[ni][r] - mrow[r]);
                s4[ni][r] = p;
                psum[r] += p;
            }
#pragma unroll
        for (int off = 1; off < 16; off <<= 1)
#pragma unroll
            for (int r = 0; r < 4; r++) psum[r] += __shfl_xor(psum[r], off, 64);
#pragma unroll
        for (int r = 0; r < 4; r++) lrow[r] = lrow[r] * scl[r] + psum[r];
#pragma unroll
        for (int di = 0; di < 5; di++)
#pragma unroll
            for (int r = 0; r < 4; r++) acc_o[di][r] *= scl[r];
#pragma unroll
        for (int ni = 0; ni < 4; ni++)
#pragma unroll
            for (int r = 0; r < 4; r++)
                Plds[wid * 1024 + (lhi * 4 + r) * 64 + ni * 16 + l15] = f2bf(s4[ni][r]);
        __syncthreads();
#pragma unroll
        for (int di = 0; di < 5; di++)
#pragma unroll
            for (int ks = 0; ks < 2; ks++) {
                bf16x8 pa = *(const bf16x8*)(Plds + wid * 1024 + l15 * 64 + ks * 32 + lhi * 8);
                bf16x8 vb = *(const bf16x8*)(Vlds + (di * 16 + l15) * 64 + ks * 32 + lhi * 8);
                acc_o[di] = __builtin_amdgcn_mfma_f32_16x16x32_bf16(pa, vb, acc_o[di], 0, 0, 0);
            }
    }

    const int h = bh & 31;
    const int b = bh >> 5;
#pragma unroll
    for (int di = 0; di < 5; di++) {
        const int col = h * HDIM + di * 16 + l15;
#pragma unroll
        for (int r = 0; r < 4; r++) {
            const int row = b * SEQ + q0 + wid * 16 + lhi * 4 + r;
            attn[(size_t)row * HIDDEN + col] = f2bf(acc_o[di][r] / lrow[r]);
        }
    }
}

extern "C" void kernel_launch(void* const* d_in, const int* in_sizes, int n_in,
                              void* d_out, int out_size, void* d_ws, size_t ws_size,
                              hipStream_t stream) {
    const int* pos = (const int*)d_in[0];
    const float* hid = (const float*)d_in[1];
    const float* Wqkv = (const float*)d_in[2];
    const float* bqkv = (const float*)d_in[3];
    const float* Wd = (const float*)d_in[4];
    const float* bd = (const float*)d_in[5];
    float* out = (float*)d_out;
    char* ws = (char*)d_ws;

    unsigned short* WqkvT = (unsigned short*)(ws);                // 39,321,600 B
    unsigned short* WdT   = (unsigned short*)(ws + 39321600);     // 13,107,200 B
    unsigned short* Xbf   = (unsigned short*)(ws + 52428800);     // 20,971,520 B
    unsigned short* qkv   = (unsigned short*)(ws + 73400320);     // 62,914,560 B
    unsigned short* Qbuf  = (unsigned short*)(ws + 136314880);    // 25,165,824 B
    unsigned short* Kbuf  = (unsigned short*)(ws + 161480704);    // 25,165,824 B
    unsigned short* Vt    = (unsigned short*)(ws + 186646528);    // 20,971,520 B
    unsigned short* attnb = Xbf;  // Xbf dead after gemm1; reuse for attention output

    cvt_kernel<<<(M_TOK * HIDDEN / 8 + 255) / 256, 256, 0, stream>>>(hid, Xbf, M_TOK * HIDDEN / 8);
    transpose_kernel<<<dim3(N_QKV / 64, HIDDEN / 64), 256, 0, stream>>>(Wqkv, WqkvT, HIDDEN, N_QKV);
    transpose_kernel<<<dim3(HIDDEN / 64, HIDDEN / 64), 256, 0, stream>>>(Wd, WdT, HIDDEN, HIDDEN);
    gemm_bt<1><<<dim3(N_QKV / 128, M_TOK / 128), 256, 0, stream>>>(Xbf, WqkvT, bqkv, qkv,
                                                                   M_TOK, N_QKV, HIDDEN);
    pack_rope_kernel<<<(64 * SEQ) / 256, 256, 0, stream>>>(qkv, pos, Qbuf, Kbuf, Vt);
    flash_kernel<<<dim3(SEQ / 64, 64), 256, 0, stream>>>(Qbuf, Kbuf, Vt, attnb);
    gemm_bt<0><<<dim3(HIDDEN / 128, M_TOK / 128), 256, 0, stream>>>(attnb, WdT, bd, out,
                                                                    M_TOK, HIDDEN, HIDDEN);
}

// Round 2
// 624.352 us; speedup vs baseline: 1.1040x; 1.1040x over previous
//
#include <hip/hip_runtime.h>

#define HIDDEN 2560
#define NHEADS 32
#define HDIM 80
#define DPAD 96
#define SEQ 2048
#define M_TOK 4096
#define N_QKV 7680
#define ATT_SCALE 0.11180339887498949f  // 80^-0.5

typedef __attribute__((ext_vector_type(4))) float f32x4;
typedef __attribute__((ext_vector_type(8))) short bf16x8;
typedef __attribute__((ext_vector_type(8))) unsigned short ushort8;

__device__ __forceinline__ unsigned short f2bf(float f) {
    unsigned int u = __float_as_uint(f);
    u += 0x7FFFu + ((u >> 16) & 1u);
    return (unsigned short)(u >> 16);
}
__device__ __forceinline__ float bf2f(unsigned short h) {
    return __uint_as_float(((unsigned int)h) << 16);
}

__device__ __forceinline__ void async_copy16(unsigned short* lds, const unsigned short* g) {
    __builtin_amdgcn_global_load_lds((const __attribute__((address_space(1))) void*)g,
                                     (__attribute__((address_space(3))) void*)lds, 16, 0, 0);
}

// ---------------- fp32 -> bf16 convert (8 elems/thread) ----------------
__global__ __launch_bounds__(256) void cvt_kernel(const float* __restrict__ in,
                                                  unsigned short* __restrict__ out, int n8) {
    int i = blockIdx.x * 256 + threadIdx.x;
    if (i >= n8) return;
    const float4* p = (const float4*)in + (size_t)i * 2;
    float4 a = p[0], b = p[1];
    ushort8 o;
    o[0] = f2bf(a.x); o[1] = f2bf(a.y); o[2] = f2bf(a.z); o[3] = f2bf(a.w);
    o[4] = f2bf(b.x); o[5] = f2bf(b.y); o[6] = f2bf(b.z); o[7] = f2bf(b.w);
    *((ushort8*)out + i) = o;
}

// ---------------- fp32 [R][C] -> bf16 [C][R] transpose ----------------
__global__ __launch_bounds__(256) void transpose_kernel(const float* __restrict__ in,
                                                        unsigned short* __restrict__ out,
                                                        int R, int C) {
    __shared__ unsigned short tile[64][66];
    const int r0 = blockIdx.y * 64, c0 = blockIdx.x * 64;
    const int t = threadIdx.x;
#pragma unroll
    for (int rep = 0; rep < 16; ++rep) {
        int idx = rep * 256 + t;
        int i = idx >> 6, j = idx & 63;
        tile[i][j] = f2bf(in[(size_t)(r0 + i) * C + (c0 + j)]);
    }
    __syncthreads();
#pragma unroll
    for (int rep = 0; rep < 16; ++rep) {
        int idx = rep * 256 + t;
        int j = idx >> 6, i = idx & 63;
        out[(size_t)(c0 + j) * R + (r0 + i)] = tile[i][j];
    }
}

// ---------------- bf16 GEMM: C[M][N] = A[M][K] * Bt[N][K]^T + bias ----------------
// 128x128 tile, BK=64, 256 threads (4 waves, 2x2), mfma 16x16x32 bf16.
// global_load_lds staging (linear LDS) with inverse-swizzled SOURCE column and
// XOR-swizzled ds_read (rule #21 both-sides swizzle) -> conflict-free frag reads.
template <int OUT_BF16>
__global__ __launch_bounds__(256) void gemm_bt(const unsigned short* __restrict__ A,
                                               const unsigned short* __restrict__ Bt,
                                               const float* __restrict__ bias,
                                               void* __restrict__ C, int M, int N, int K) {
    __shared__ __align__(16) unsigned short Alds[128 * 64];
    __shared__ __align__(16) unsigned short Blds[128 * 64];
    const int t = threadIdx.x;
    const int lane = t & 63, wid = t >> 6;
    const int wm = wid >> 1, wn = wid & 1;
    const int l15 = lane & 15, lhi = lane >> 4;
    const int bm = blockIdx.y * 128, bn = blockIdx.x * 128;

    f32x4 acc[4][4] = {};

    int grow[4], gcol[4];
#pragma unroll
    for (int c = 0; c < 4; ++c) {
        int q = t + c * 256;
        grow[c] = q >> 3;
        gcol[c] = ((q & 7) ^ (grow[c] & 7)) * 8;  // pre-swizzled source column
    }
    const size_t arow0 = (size_t)bm * K, brow0 = (size_t)bn * K;
    const int arow = wm * 64 + l15;  // + i*16 (i*16 doesn't change &7)
    const int brow = wn * 64 + l15;
    const int r7 = l15 & 7;

    for (int k0 = 0; k0 < K; k0 += 64) {
        __syncthreads();
#pragma unroll
        for (int c = 0; c < 4; ++c)
            async_copy16(Alds + (t + c * 256) * 8,
                         A + arow0 + (size_t)grow[c] * K + k0 + gcol[c]);
#pragma unroll
        for (int c = 0; c < 4; ++c)
            async_copy16(Blds + (t + c * 256) * 8,
                         Bt + brow0 + (size_t)grow[c] * K + k0 + gcol[c]);
        __syncthreads();
#pragma unroll
        for (int kk = 0; kk < 2; ++kk) {
            const int soff = ((kk * 4 + lhi) ^ r7) * 8;
            bf16x8 af[4], bfv[4];
#pragma unroll
            for (int i = 0; i < 4; i++)
                af[i] = *(const bf16x8*)(Alds + (arow + i * 16) * 64 + soff);
#pragma unroll
            for (int j = 0; j < 4; j++)
                bfv[j] = *(const bf16x8*)(Blds + (brow + j * 16) * 64 + soff);
#pragma unroll
            for (int i = 0; i < 4; i++)
#pragma unroll
                for (int j = 0; j < 4; j++)
                    acc[i][j] = __builtin_amdgcn_mfma_f32_16x16x32_bf16(af[i], bfv[j], acc[i][j], 0, 0, 0);
        }
    }

#pragma unroll
    for (int j = 0; j < 4; j++) {
        const int col = bn + wn * 64 + j * 16 + l15;
        const float bv = bias[col];
#pragma unroll
        for (int i = 0; i < 4; i++) {
            const int row0 = bm + wm * 64 + i * 16 + lhi * 4;
#pragma unroll
            for (int r = 0; r < 4; r++) {
                float v = acc[i][j][r] + bv;
                if (OUT_BF16)
                    ((unsigned short*)C)[(size_t)(row0 + r) * N + col] = f2bf(v);
                else
                    ((float*)C)[(size_t)(row0 + r) * N + col] = v;
            }
        }
    }
}

// ---------------- pack qkv -> Q,K (rope, pad to 96), Vt (transposed) ----------------
__global__ __launch_bounds__(256) void pack_rope_kernel(const unsigned short* __restrict__ qkv,
                                                        const int* __restrict__ pos_ids,
                                                        unsigned short* __restrict__ Qb,
                                                        unsigned short* __restrict__ Kb,
                                                        unsigned short* __restrict__ Vt) {
    int g = blockIdx.x * 256 + threadIdx.x;  // (b*32+h)*2048 + s
    int s = g & (SEQ - 1);
    int bh = g >> 11;
    int b = bh >> 5;
    int h = bh & 31;
    int m = b * SEQ + s;
    const unsigned short* base = qkv + (size_t)m * N_QKV + h * HDIM;
    unsigned short* Qrow = Qb + ((size_t)bh * SEQ + s) * DPAD;
    unsigned short* Krow = Kb + ((size_t)bh * SEQ + s) * DPAD;
    unsigned short* Vcol = Vt + (size_t)bh * HDIM * SEQ + s;

    float pos = (float)pos_ids[m];
    float qv[32], kv[32];
#pragma unroll
    for (int c = 0; c < 4; ++c) {
        ushort8 qc = *(const ushort8*)(base + c * 8);
        ushort8 kc = *(const ushort8*)(base + HIDDEN + c * 8);
#pragma unroll
        for (int j = 0; j < 8; ++j) {
            qv[c * 8 + j] = bf2f(qc[j]);
            kv[c * 8 + j] = bf2f(kc[j]);
        }
    }
#pragma unroll
    for (int d = 0; d < 16; ++d) {
        float inv = __expf(-(float)d * 0.5756462732485115f);  // ln(10000)/16
        float ang = pos * inv;
        float sn, cs;
        __sincosf(ang, &sn, &cs);
        float x1 = qv[d], x2 = qv[d + 16];
        qv[d] = x1 * cs - x2 * sn;
        qv[d + 16] = x2 * cs + x1 * sn;
        x1 = kv[d]; x2 = kv[d + 16];
        kv[d] = x1 * cs - x2 * sn;
        kv[d + 16] = x2 * cs + x1 * sn;
    }
#pragma unroll
    for (int c = 0; c < 4; ++c) {
        ushort8 qo, ko;
#pragma unroll
        for (int j = 0; j < 8; ++j) {
            qo[j] = f2bf(qv[c * 8 + j]);
            ko[j] = f2bf(kv[c * 8 + j]);
        }
        *(ushort8*)(Qrow + c * 8) = qo;
        *(ushort8*)(Krow + c * 8) = ko;
    }
#pragma unroll
    for (int c = 4; c < 10; ++c) {
        *(ushort8*)(Qrow + c * 8) = *(const ushort8*)(base + c * 8);
        *(ushort8*)(Krow + c * 8) = *(const ushort8*)(base + HIDDEN + c * 8);
    }
    ushort8 z = {0, 0, 0, 0, 0, 0, 0, 0};
    *(ushort8*)(Qrow + 80) = z;
    *(ushort8*)(Qrow + 88) = z;
    *(ushort8*)(Krow + 80) = z;
    *(ushort8*)(Krow + 88) = z;
#pragma unroll
    for (int d = 0; d < HDIM; ++d) Vcol[(size_t)d * SEQ] = base[2 * HIDDEN + d];
}

// ---------------- causal flash attention v2 ----------------
// grid: (B*H, S/128) with q-block reversed (heavy first). 4 waves x 32 q-rows.
// K-tile 64. Padded LDS (conflict-free), register prefetch of next K/V tile,
// wave-private P (no 3rd barrier), per-fragment causal skip.
#define KSTR 104  // Klds row stride (shorts): 208B -> 2-way (free)
#define VSTR 72   // Vlds/Plds row stride: 144B -> 2-way (free)
__global__ __launch_bounds__(256) void flash_kernel(const unsigned short* __restrict__ Qb,
                                                    const unsigned short* __restrict__ Kb,
                                                    const unsigned short* __restrict__ Vt,
                                                    unsigned short* __restrict__ attn) {
    __shared__ __align__(16) unsigned short Klds[64 * KSTR];
    __shared__ __align__(16) unsigned short Vlds[80 * VSTR];
    __shared__ __align__(16) unsigned short Plds[128 * VSTR];

    const int bh = blockIdx.x;
    const int qb = (int)gridDim.y - 1 - (int)blockIdx.y;  // heavy blocks dispatch first
    const int q0 = qb * 128;
    const int nkt = qb * 2 + 2;
    const int t = threadIdx.x, lane = t & 63, wid = t >> 6;
    const int l15 = lane & 15, lhi = lane >> 4;

    // staging address constants
    int krow[3], kcol[3], kldso[3];
#pragma unroll
    for (int c = 0; c < 3; ++c) {
        int q = t + c * 256;
        krow[c] = q / 12;
        kcol[c] = (q % 12) * 8;
        kldso[c] = krow[c] * KSTR + kcol[c];
    }
    int vd[3], vs[3], vldso[3];
#pragma unroll
    for (int c = 0; c < 3; ++c) {
        int q = t + c * 256;
        vd[c] = q >> 3;
        vs[c] = (q & 7) * 8;
        vldso[c] = vd[c] * VSTR + vs[c];
    }
    const unsigned short* Kbase = Kb + (size_t)bh * SEQ * DPAD;
    const unsigned short* Vbase = Vt + (size_t)bh * HDIM * SEQ;

    // Q fragments: 2 row-fragments x 3 k-chunks
    bf16x8 qf[2][3];
#pragma unroll
    for (int i = 0; i < 2; ++i) {
        const unsigned short* Qrow =
            Qb + ((size_t)bh * SEQ + q0 + wid * 32 + i * 16 + l15) * DPAD + lhi * 8;
#pragma unroll
        for (int kk = 0; kk < 3; kk++) qf[i][kk] = *(const bf16x8*)(Qrow + kk * 32);
    }

    f32x4 acc_o[2][5] = {};
    float mrow[2][4], lrow[2][4];
#pragma unroll
    for (int i = 0; i < 2; ++i)
#pragma unroll
        for (int r = 0; r < 4; r++) { mrow[i][r] = -1e30f; lrow[i][r] = 0.f; }

    // prologue: prefetch tile 0 into regs
    ushort8 kreg[3], vreg[3];
#pragma unroll
    for (int c = 0; c < 3; ++c) kreg[c] = *(const ushort8*)(Kbase + (size_t)krow[c] * DPAD + kcol[c]);
#pragma unroll
    for (int c = 0; c < 2; ++c) vreg[c] = *(const ushort8*)(Vbase + (size_t)vd[c] * SEQ + vs[c]);
    if (t < 128) vreg[2] = *(const ushort8*)(Vbase + (size_t)vd[2] * SEQ + vs[2]);

    for (int kt = 0; kt < nkt; ++kt) {
        const int k0 = kt * 64;
        __syncthreads();  // A: prev tile's LDS reads done (drains prefetch vmcnt)
#pragma unroll
        for (int c = 0; c < 3; ++c) *(ushort8*)(Klds + kldso[c]) = kreg[c];
#pragma unroll
        for (int c = 0; c < 2; ++c) *(ushort8*)(Vlds + vldso[c]) = vreg[c];
        if (t < 128) *(ushort8*)(Vlds + vldso[2]) = vreg[2];
        __syncthreads();  // B: tile visible
        if (kt + 1 < nkt) {  // prefetch next tile; latency hides under compute below
            const int k0n = k0 + 64;
#pragma unroll
            for (int c = 0; c < 3; ++c)
                kreg[c] = *(const ushort8*)(Kbase + (size_t)(k0n + krow[c]) * DPAD + kcol[c]);
#pragma unroll
            for (int c = 0; c < 2; ++c)
                vreg[c] = *(const ushort8*)(Vbase + (size_t)vd[c] * SEQ + k0n + vs[c]);
            if (t < 128) vreg[2] = *(const ushort8*)(Vbase + (size_t)vd[2] * SEQ + k0n + vs[2]);
        }

        const bool live0 = (k0 <= q0 + wid * 32 + 15);
        const bool live1 = (k0 <= q0 + wid * 32 + 16 + 15);

        // QK^T: B-fragments shared across both row-fragments
        f32x4 s4[2][4] = {};
#pragma unroll
        for (int ni = 0; ni < 4; ni++) {
            const int krr = (ni * 16 + l15) * KSTR + lhi * 8;
#pragma unroll
            for (int kk = 0; kk < 3; kk++) {
                bf16x8 bk = *(const bf16x8*)(Klds + krr + kk * 32);
                if (live0) s4[0][ni] = __builtin_amdgcn_mfma_f32_16x16x32_bf16(qf[0][kk], bk, s4[0][ni], 0, 0, 0);
                if (live1) s4[1][ni] = __builtin_amdgcn_mfma_f32_16x16x32_bf16(qf[1][kk], bk, s4[1][ni], 0, 0, 0);
            }
        }

        // softmax per row-fragment
#pragma unroll
        for (int i = 0; i < 2; ++i) {
            if (!(i ? live1 : live0)) continue;
            const int rowg = q0 + wid * 32 + i * 16 + lhi * 4;
            float pmax[4] = {-1e30f, -1e30f, -1e30f, -1e30f};
#pragma unroll
            for (int ni = 0; ni < 4; ni++) {
                const int colg = k0 + ni * 16 + l15;
#pragma unroll
                for (int r = 0; r < 4; r++) {
                    float v = s4[i][ni][r] * ATT_SCALE;
                    v = (colg <= rowg + r) ? v : -1e30f;
                    s4[i][ni][r] = v;
                    pmax[r] = fmaxf(pmax[r], v);
                }
            }
#pragma unroll
            for (int off = 1; off < 16; off <<= 1)
#pragma unroll
                for (int r = 0; r < 4; r++) pmax[r] = fmaxf(pmax[r], __shfl_xor(pmax[r], off, 64));
            float scl[4], psum[4];
#pragma unroll
            for (int r = 0; r < 4; r++) {
                float mnew = fmaxf(mrow[i][r], pmax[r]);
                scl[r] = __expf(mrow[i][r] - mnew);
                mrow[i][r] = mnew;
                psum[r] = 0.f;
            }
#pragma unroll
            for (int ni = 0; ni < 4; ni++)
#pragma unroll
                for (int r = 0; r < 4; r++) {
                    float p = __expf(s4[i][ni][r] - mrow[i][r]);
                    s4[i][ni][r] = p;
                    psum[r] += p;
                }
#pragma unroll
            for (int off = 1; off < 16; off <<= 1)
#pragma unroll
                for (int r = 0; r < 4; r++) psum[r] += __shfl_xor(psum[r], off, 64);
#pragma unroll
            for (int r = 0; r < 4; r++) lrow[i][r] = lrow[i][r] * scl[r] + psum[r];
#pragma unroll
            for (int di = 0; di < 5; di++)
#pragma unroll
                for (int r = 0; r < 4; r++) acc_o[i][di][r] *= scl[r];
            // P -> wave-private LDS (no barrier needed; lgkmcnt orders within wave)
#pragma unroll
            for (int ni = 0; ni < 4; ni++)
#pragma unroll
                for (int r = 0; r < 4; r++)
                    Plds[(wid * 32 + i * 16 + lhi * 4 + r) * VSTR + ni * 16 + l15] = f2bf(s4[i][ni][r]);
        }

        // PV: P-fragments hoisted, V-fragments shared across both row-fragments
        bf16x8 pa[2][2];
#pragma unroll
        for (int i = 0; i < 2; ++i) {
            if (!(i ? live1 : live0)) continue;
#pragma unroll
            for (int ks = 0; ks < 2; ks++)
                pa[i][ks] = *(const bf16x8*)(Plds + (wid * 32 + i * 16 + l15) * VSTR + ks * 32 + lhi * 8);
        }
#pragma unroll
        for (int di = 0; di < 5; di++) {
#pragma unroll
            for (int ks = 0; ks < 2; ks++) {
                bf16x8 vb = *(const bf16x8*)(Vlds + (di * 16 + l15) * VSTR + ks * 32 + lhi * 8);
                if (live0) acc_o[0][di] = __builtin_amdgcn_mfma_f32_16x16x32_bf16(pa[0][ks], vb, acc_o[0][di], 0, 0, 0);
                if (live1) acc_o[1][di] = __builtin_amdgcn_mfma_f32_16x16x32_bf16(pa[1][ks], vb, acc_o[1][di], 0, 0, 0);
            }
        }
    }

    const int h = bh & 31;
    const int b = bh >> 5;
#pragma unroll
    for (int i = 0; i < 2; ++i)
#pragma unroll
        for (int di = 0; di < 5; di++) {
            const int col = h * HDIM + di * 16 + l15;
#pragma unroll
            for (int r = 0; r < 4; r++) {
                const int row = b * SEQ + q0 + wid * 32 + i * 16 + lhi * 4 + r;
                attn[(size_t)row * HIDDEN + col] = f2bf(acc_o[i][di][r] / lrow[i][r]);
            }
        }
}

extern "C" void kernel_launch(void* const* d_in, const int* in_sizes, int n_in,
                              void* d_out, int out_size, void* d_ws, size_t ws_size,
                              hipStream_t stream) {
    const int* pos = (const int*)d_in[0];
    const float* hid = (const float*)d_in[1];
    const float* Wqkv = (const float*)d_in[2];
    const float* bqkv = (const float*)d_in[3];
    const float* Wd = (const float*)d_in[4];
    const float* bd = (const float*)d_in[5];
    float* out = (float*)d_out;
    char* ws = (char*)d_ws;

    unsigned short* WqkvT = (unsigned short*)(ws);                // 39,321,600 B
    unsigned short* WdT   = (unsigned short*)(ws + 39321600);     // 13,107,200 B
    unsigned short* Xbf   = (unsigned short*)(ws + 52428800);     // 20,971,520 B
    unsigned short* qkv   = (unsigned short*)(ws + 73400320);     // 62,914,560 B
    unsigned short* Qbuf  = (unsigned short*)(ws + 136314880);    // 25,165,824 B
    unsigned short* Kbuf  = (unsigned short*)(ws + 161480704);    // 25,165,824 B
    unsigned short* Vt    = (unsigned short*)(ws + 186646528);    // 20,971,520 B
    unsigned short* attnb = Xbf;  // Xbf dead after gemm1; reuse for attention output

    cvt_kernel<<<(M_TOK * HIDDEN / 8 + 255) / 256, 256, 0, stream>>>(hid, Xbf, M_TOK * HIDDEN / 8);
    transpose_kernel<<<dim3(N_QKV / 64, HIDDEN / 64), 256, 0, stream>>>(Wqkv, WqkvT, HIDDEN, N_QKV);
    transpose_kernel<<<dim3(HIDDEN / 64, HIDDEN / 64), 256, 0, stream>>>(Wd, WdT, HIDDEN, HIDDEN);
    gemm_bt<1><<<dim3(N_QKV / 128, M_TOK / 128), 256, 0, stream>>>(Xbf, WqkvT, bqkv, qkv,
                                                                   M_TOK, N_QKV, HIDDEN);
    pack_rope_kernel<<<(64 * SEQ) / 256, 256, 0, stream>>>(qkv, pos, Qbuf, Kbuf, Vt);
    flash_kernel<<<dim3(64, SEQ / 128), 256, 0, stream>>>(Qbuf, Kbuf, Vt, attnb);
    gemm_bt<0><<<dim3(HIDDEN / 128, M_TOK / 128), 256, 0, stream>>>(attnb, WdT, bd, out,
                                                                    M_TOK, HIDDEN, HIDDEN);
}

// Round 6
// 488.492 us; speedup vs baseline: 1.4111x; 1.2781x over previous
//
#include <hip/hip_runtime.h>

#define HIDDEN 2560
#define NHEADS 32
#define HDIM 80
#define DPAD 96
#define SEQ 2048
#define M_TOK 4096
#define N_QKV 7680
#define ATT_SCALE 0.11180339887498949f  // 80^-0.5

typedef __attribute__((ext_vector_type(4))) float f32x4;
typedef __attribute__((ext_vector_type(16))) float f32x16;
typedef __attribute__((ext_vector_type(4))) int i32x4;
typedef __attribute__((ext_vector_type(8))) short bf16x8;
typedef __attribute__((ext_vector_type(8))) unsigned short ushort8;

__device__ __forceinline__ unsigned short f2bf(float f) {
    unsigned int u = __float_as_uint(f);
    u += 0x7FFFu + ((u >> 16) & 1u);
    return (unsigned short)(u >> 16);
}
__device__ __forceinline__ float bf2f(unsigned short h) {
    return __uint_as_float(((unsigned int)h) << 16);
}

__device__ __forceinline__ void async_copy16(unsigned short* lds, const unsigned short* g) {
    __builtin_amdgcn_global_load_lds((const __attribute__((address_space(1))) void*)g,
                                     (__attribute__((address_space(3))) void*)lds, 16, 0, 0);
}

__device__ __forceinline__ int cvt_pk_bf16(float lo, float hi) {
    int d;
    asm("v_cvt_pk_bf16_f32 %0, %1, %2" : "=v"(d) : "v"(lo), "v"(hi));
    return d;
}

// ---------------- fp32 -> bf16 convert (8 elems/thread) ----------------
__global__ __launch_bounds__(256) void cvt_kernel(const float* __restrict__ in,
                                                  unsigned short* __restrict__ out, int n8) {
    int i = blockIdx.x * 256 + threadIdx.x;
    if (i >= n8) return;
    const float4* p = (const float4*)in + (size_t)i * 2;
    float4 a = p[0], b = p[1];
    ushort8 o;
    o[0] = f2bf(a.x); o[1] = f2bf(a.y); o[2] = f2bf(a.z); o[3] = f2bf(a.w);
    o[4] = f2bf(b.x); o[5] = f2bf(b.y); o[6] = f2bf(b.z); o[7] = f2bf(b.w);
    *((ushort8*)out + i) = o;
}

// ---------------- fp32 [R][C] -> bf16 [C][R] transpose ----------------
__global__ __launch_bounds__(256) void transpose_kernel(const float* __restrict__ in,
                                                        unsigned short* __restrict__ out,
                                                        int R, int C) {
    __shared__ unsigned short tile[64][66];
    const int r0 = blockIdx.y * 64, c0 = blockIdx.x * 64;
    const int t = threadIdx.x;
#pragma unroll
    for (int rep = 0; rep < 16; ++rep) {
        int idx = rep * 256 + t;
        int i = idx >> 6, j = idx & 63;
        tile[i][j] = f2bf(in[(size_t)(r0 + i) * C + (c0 + j)]);
    }
    __syncthreads();
#pragma unroll
    for (int rep = 0; rep < 16; ++rep) {
        int idx = rep * 256 + t;
        int j = idx >> 6, i = idx & 63;
        out[(size_t)(c0 + j) * R + (r0 + i)] = tile[i][j];
    }
}

// ---------------- bf16 GEMM: C[M][N] = A[M][K] * Bt[N][K]^T + bias ----------------
template <int OUT_BF16>
__global__ __launch_bounds__(256) void gemm_bt(const unsigned short* __restrict__ A,
                                               const unsigned short* __restrict__ Bt,
                                               const float* __restrict__ bias,
                                               void* __restrict__ C, int M, int N, int K) {
    __shared__ __align__(16) unsigned short Alds[128 * 64];
    __shared__ __align__(16) unsigned short Blds[128 * 64];
    const int t = threadIdx.x;
    const int lane = t & 63, wid = t >> 6;
    const int wm = wid >> 1, wn = wid & 1;
    const int l15 = lane & 15, lhi = lane >> 4;
    const int bm = blockIdx.y * 128, bn = blockIdx.x * 128;

    f32x4 acc[4][4] = {};

    int grow[4], gcol[4];
#pragma unroll
    for (int c = 0; c < 4; ++c) {
        int q = t + c * 256;
        grow[c] = q >> 3;
        gcol[c] = ((q & 7) ^ (grow[c] & 7)) * 8;  // pre-swizzled source column
    }
    const size_t arow0 = (size_t)bm * K, brow0 = (size_t)bn * K;
    const int arow = wm * 64 + l15;
    const int brow = wn * 64 + l15;
    const int r7 = l15 & 7;

    for (int k0 = 0; k0 < K; k0 += 64) {
        __syncthreads();
#pragma unroll
        for (int c = 0; c < 4; ++c)
            async_copy16(Alds + (t + c * 256) * 8,
                         A + arow0 + (size_t)grow[c] * K + k0 + gcol[c]);
#pragma unroll
        for (int c = 0; c < 4; ++c)
            async_copy16(Blds + (t + c * 256) * 8,
                         Bt + brow0 + (size_t)grow[c] * K + k0 + gcol[c]);
        __syncthreads();
#pragma unroll
        for (int kk = 0; kk < 2; ++kk) {
            const int soff = ((kk * 4 + lhi) ^ r7) * 8;
            bf16x8 af[4], bfv[4];
#pragma unroll
            for (int i = 0; i < 4; i++)
                af[i] = *(const bf16x8*)(Alds + (arow + i * 16) * 64 + soff);
#pragma unroll
            for (int j = 0; j < 4; j++)
                bfv[j] = *(const bf16x8*)(Blds + (brow + j * 16) * 64 + soff);
#pragma unroll
            for (int i = 0; i < 4; i++)
#pragma unroll
                for (int j = 0; j < 4; j++)
                    acc[i][j] = __builtin_amdgcn_mfma_f32_16x16x32_bf16(af[i], bfv[j], acc[i][j], 0, 0, 0);
        }
    }

#pragma unroll
    for (int j = 0; j < 4; j++) {
        const int col = bn + wn * 64 + j * 16 + l15;
        const float bv = bias[col];
#pragma unroll
        for (int i = 0; i < 4; i++) {
            const int row0 = bm + wm * 64 + i * 16 + lhi * 4;
#pragma unroll
            for (int r = 0; r < 4; r++) {
                float v = acc[i][j][r] + bv;
                if (OUT_BF16)
                    ((unsigned short*)C)[(size_t)(row0 + r) * N + col] = f2bf(v);
                else
                    ((float*)C)[(size_t)(row0 + r) * N + col] = v;
            }
        }
    }
}

// ---------------- pack qkv -> Q (rope+scale, pad 96), K (rope, pad 96), Vt ----------------
__global__ __launch_bounds__(256) void pack_rope_kernel(const unsigned short* __restrict__ qkv,
                                                        const int* __restrict__ pos_ids,
                                                        unsigned short* __restrict__ Qb,
                                                        unsigned short* __restrict__ Kb,
                                                        unsigned short* __restrict__ Vt) {
    int g = blockIdx.x * 256 + threadIdx.x;  // (b*32+h)*2048 + s
    int s = g & (SEQ - 1);
    int bh = g >> 11;
    int b = bh >> 5;
    int h = bh & 31;
    int m = b * SEQ + s;
    const unsigned short* base = qkv + (size_t)m * N_QKV + h * HDIM;
    unsigned short* Qrow = Qb + ((size_t)bh * SEQ + s) * DPAD;
    unsigned short* Krow = Kb + ((size_t)bh * SEQ + s) * DPAD;
    unsigned short* Vcol = Vt + (size_t)bh * HDIM * SEQ + s;

    float pos = (float)pos_ids[m];
    float qv[32], kv[32];
#pragma unroll
    for (int c = 0; c < 4; ++c) {
        ushort8 qc = *(const ushort8*)(base + c * 8);
        ushort8 kc = *(const ushort8*)(base + HIDDEN + c * 8);
#pragma unroll
        for (int j = 0; j < 8; ++j) {
            qv[c * 8 + j] = bf2f(qc[j]);
            kv[c * 8 + j] = bf2f(kc[j]);
        }
    }
#pragma unroll
    for (int d = 0; d < 16; ++d) {
        float inv = __expf(-(float)d * 0.5756462732485115f);  // ln(10000)/16
        float ang = pos * inv;
        float sn, cs;
        __sincosf(ang, &sn, &cs);
        float qcs = cs * ATT_SCALE, qsn = sn * ATT_SCALE;  // fold softmax scale into Q
        float x1 = qv[d], x2 = qv[d + 16];
        qv[d] = x1 * qcs - x2 * qsn;
        qv[d + 16] = x2 * qcs + x1 * qsn;
        x1 = kv[d]; x2 = kv[d + 16];
        kv[d] = x1 * cs - x2 * sn;
        kv[d + 16] = x2 * cs + x1 * sn;
    }
#pragma unroll
    for (int c = 0; c < 4; ++c) {
        ushort8 qo, ko;
#pragma unroll
        for (int j = 0; j < 8; ++j) {
            qo[j] = f2bf(qv[c * 8 + j]);
            ko[j] = f2bf(kv[c * 8 + j]);
        }
        *(ushort8*)(Qrow + c * 8) = qo;
        *(ushort8*)(Krow + c * 8) = ko;
    }
#pragma unroll
    for (int c = 4; c < 10; ++c) {
        ushort8 qc = *(const ushort8*)(base + c * 8);
        ushort8 qo;
#pragma unroll
        for (int j = 0; j < 8; ++j) qo[j] = f2bf(bf2f(qc[j]) * ATT_SCALE);
        *(ushort8*)(Qrow + c * 8) = qo;
        *(ushort8*)(Krow + c * 8) = *(const ushort8*)(base + HIDDEN + c * 8);
    }
    ushort8 z = {0, 0, 0, 0, 0, 0, 0, 0};
    *(ushort8*)(Qrow + 80) = z;
    *(ushort8*)(Qrow + 88) = z;
    *(ushort8*)(Krow + 80) = z;
    *(ushort8*)(Krow + 88) = z;
#pragma unroll
    for (int d = 0; d < HDIM; ++d) Vcol[(size_t)d * SEQ] = base[2 * HIDDEN + d];
}

// ---------------- causal flash attention v3: swapped QK^T, in-register softmax ----------------
// 8 waves x 32 q-rows (QBLK=256), KVBLK=64, mfma 32x32x16.
// S^T = mfma(K, Q): lane holds its q-row's scores lane-locally.
// K LDS [64][128] xor-swz; V LDS [96][64] xor-swz (rows 80..95 zeroed once).
// P h-half exchange via __shfl_xor (unambiguous semantics); permlane A/B deferred.
__global__ __launch_bounds__(512) void flash_kernel(const unsigned short* __restrict__ Qb,
                                                    const unsigned short* __restrict__ Kb,
                                                    const unsigned short* __restrict__ Vt,
                                                    unsigned short* __restrict__ attn) {
    __shared__ __align__(16) unsigned short Klds[64 * 128];
    __shared__ __align__(16) unsigned short Vlds[96 * 64];

    const int bh = blockIdx.x;
    const int qb = 7 - (int)blockIdx.y;  // heavy blocks dispatch first
    const int q0b = qb * 256;
    const int nkt = 4 * qb + 4;
    const int t = threadIdx.x;
    const int lane = t & 63, wid = t >> 6;
    const int l31 = lane & 31, h = lane >> 5, l7 = lane & 7;
    const int q0w = q0b + wid * 32;
    const int swz = l7 << 3;  // xor on shorts-offset (== (row&7)<<4 bytes)

    const unsigned short* Kbase = Kb + (size_t)bh * SEQ * DPAD;
    const unsigned short* Vbase = Vt + (size_t)bh * HDIM * SEQ;

    // Q B-frags: lane holds q-row (l31), d-slice h*8 per 16-d chunk
    bf16x8 qf[6];
    {
        const unsigned short* Qrow = Qb + ((size_t)bh * SEQ + q0w + l31) * DPAD + h * 8;
#pragma unroll
        for (int dc = 0; dc < 6; ++dc) qf[dc] = *(const bf16x8*)(Qrow + dc * 16);
    }

    // zero V pad rows 80..95 once (512 ints == 16 rows * 128B)
    ((int*)Vlds)[2560 + t] = 0;

    f32x16 acc0 = {}, acc1 = {}, acc2 = {};
    float mrow = -1e30f, lrow = 0.f;

    // staging constants: K 768x16B chunks (global-linear), V 640x16B chunks
    const int kidx1 = 512 + t;
    const int kr0 = t / 12, kc0 = t % 12;
    const int kr1 = kidx1 / 12, kc1 = kidx1 % 12;
    const int vr0 = t >> 3, vc0 = t & 7;
    const int vr1 = (512 + t) >> 3, vc1 = t & 7;
    const int kd0 = kr0 * 128 + ((kc0 * 8) ^ ((kr0 & 7) << 3));
    const int kd1 = kr1 * 128 + ((kc1 * 8) ^ ((kr1 & 7) << 3));
    const int vd0 = vr0 * 64 + ((vc0 * 8) ^ ((vr0 & 7) << 3));
    const int vd1 = vr1 * 64 + ((vc1 * 8) ^ ((vr1 & 7) << 3));

    ushort8 kreg0, kreg1, vreg0, vreg1;
    kreg0 = *(const ushort8*)(Kbase + (size_t)t * 8);
    if (t < 256) kreg1 = *(const ushort8*)(Kbase + (size_t)kidx1 * 8);
    vreg0 = *(const ushort8*)(Vbase + (size_t)vr0 * SEQ + vc0 * 8);
    if (t < 128) vreg1 = *(const ushort8*)(Vbase + (size_t)vr1 * SEQ + vc1 * 8);

    for (int kt = 0; kt < nkt; ++kt) {
        const int k0 = kt * 64;
        __syncthreads();  // prev tile's LDS reads done
        *(ushort8*)(Klds + kd0) = kreg0;
        if (t < 256) *(ushort8*)(Klds + kd1) = kreg1;
        *(ushort8*)(Vlds + vd0) = vreg0;
        if (t < 128) *(ushort8*)(Vlds + vd1) = vreg1;
        __syncthreads();  // tile visible
        if (kt + 1 < nkt) {  // prefetch next tile; hides under compute
            const int kn = k0 + 64;
            kreg0 = *(const ushort8*)(Kbase + (size_t)kn * DPAD + (size_t)t * 8);
            if (t < 256) kreg1 = *(const ushort8*)(Kbase + (size_t)kn * DPAD + (size_t)kidx1 * 8);
            vreg0 = *(const ushort8*)(Vbase + (size_t)vr0 * SEQ + kn + vc0 * 8);
            if (t < 128) vreg1 = *(const ushort8*)(Vbase + (size_t)vr1 * SEQ + kn + vc1 * 8);
        }
        if (k0 > q0w + 31) continue;  // wave fully masked (barriers already passed)

        // ---- QK^T swapped: S^T[k][q] ----
        f32x16 s0 = {}, s1 = {};
        __builtin_amdgcn_s_setprio(1);
#pragma unroll
        for (int dc = 0; dc < 6; ++dc) {
            const int co = (dc * 16 + h * 8) ^ swz;
            bf16x8 ka = *(const bf16x8*)(Klds + l31 * 128 + co);
            bf16x8 kb2 = *(const bf16x8*)(Klds + (32 + l31) * 128 + co);
            s0 = __builtin_amdgcn_mfma_f32_32x32x16_bf16(ka, qf[dc], s0, 0, 0, 0);
            s1 = __builtin_amdgcn_mfma_f32_32x32x16_bf16(kb2, qf[dc], s1, 0, 0, 0);
        }
        __builtin_amdgcn_s_setprio(0);

        const int qg = q0w + l31;
        if (k0 + 63 > q0w) {  // boundary tile: causal mask
#pragma unroll
            for (int r = 0; r < 16; ++r) {
                const int kg = k0 + (r & 3) + 8 * (r >> 2) + 4 * h;
                if (kg > qg) s0[r] = -2e30f;
                if (kg + 32 > qg) s1[r] = -2e30f;
            }
        }
        // ---- in-register online softmax (row = lane-local) ----
        float pmax = s0[0];
#pragma unroll
        for (int r = 1; r < 16; ++r) pmax = fmaxf(pmax, s0[r]);
#pragma unroll
        for (int r = 0; r < 16; ++r) pmax = fmaxf(pmax, s1[r]);
        pmax = fmaxf(pmax, __shfl_xor(pmax, 32, 64));  // combine partner half (same q-row)
        if (!__all(pmax <= mrow + 8.0f)) {  // defer-max (exact)
            float mnew = fmaxf(mrow, pmax);
            float scl = __expf(mrow - mnew);
            mrow = mnew;
            lrow *= scl;
#pragma unroll
            for (int r = 0; r < 16; ++r) {
                float sq = __shfl(scl, (r & 3) + 8 * (r >> 2) + 4 * h, 64);
                acc0[r] *= sq; acc1[r] *= sq; acc2[r] *= sq;
            }
        }
        float ps = 0.f;
#pragma unroll
        for (int r = 0; r < 16; ++r) { s0[r] = __expf(s0[r] - mrow); ps += s0[r]; }
#pragma unroll
        for (int r = 0; r < 16; ++r) { s1[r] = __expf(s1[r] - mrow); ps += s1[r]; }
        lrow += ps + __shfl_xor(ps, 32, 64);  // own + partner half
        // ---- P pack to A-frags: cvt_pk + shfl_xor half-exchange ----
        // A-frag target (linear k-map g(h,j)=8h+j): lane h=0 word w0..w3 = P[k 0..7];
        // h=1 words = P[k 8..15] (per 16-k chunk). Own slots: h's pk0/pk1 hold
        // k{4h+0..3}/k{8+4h+0..3}; partner's fill the rest.
        i32x4 af[2][2];
#pragma unroll
        for (int ks = 0; ks < 2; ++ks) {
            const f32x16& sv = ks ? s1 : s0;
            int pk0[2], pk1[2], pk2[2], pk3[2];
#pragma unroll
            for (int i = 0; i < 2; ++i) {
                pk0[i] = cvt_pk_bf16(sv[2 * i], sv[2 * i + 1]);
                pk1[i] = cvt_pk_bf16(sv[4 + 2 * i], sv[5 + 2 * i]);
                pk2[i] = cvt_pk_bf16(sv[8 + 2 * i], sv[9 + 2 * i]);
                pk3[i] = cvt_pk_bf16(sv[12 + 2 * i], sv[13 + 2 * i]);
            }
#pragma unroll
            for (int i = 0; i < 2; ++i) {
                const int o0 = __shfl_xor(pk0[i], 32, 64);  // partner's pk0
                const int o1 = __shfl_xor(pk1[i], 32, 64);  // partner's pk1
                af[ks][0][i]     = h ? o1     : pk0[i];  // w01: k{8h..8h+3}
                af[ks][0][2 + i] = h ? pk1[i] : o0;      // w23: k{8h+4..8h+7}
                const int o2 = __shfl_xor(pk2[i], 32, 64);
                const int o3 = __shfl_xor(pk3[i], 32, 64);
                af[ks][1][i]     = h ? o3     : pk2[i];
                af[ks][1][2 + i] = h ? pk3[i] : o2;
            }
        }
        // ---- PV: O[q][d] ----
        __builtin_amdgcn_s_setprio(1);
#pragma unroll
        for (int ds = 0; ds < 3; ++ds) {
            f32x16& ac = ds == 0 ? acc0 : (ds == 1 ? acc1 : acc2);
            const int vrow = (ds * 32 + l31) * 64;
#pragma unroll
            for (int ks = 0; ks < 2; ++ks)
#pragma unroll
                for (int kh = 0; kh < 2; ++kh) {
                    bf16x8 vb = *(const bf16x8*)(Vlds + vrow + ((ks * 32 + kh * 16 + h * 8) ^ swz));
                    bf16x8 pa = __builtin_bit_cast(bf16x8, af[ks][kh]);
                    ac = __builtin_amdgcn_mfma_f32_32x32x16_bf16(pa, vb, ac, 0, 0, 0);
                }
        }
        __builtin_amdgcn_s_setprio(0);
    }

    // ---- epilogue ----
    const int hh = bh & 31, b = bh >> 5;
    const float linv = 1.0f / lrow;
#pragma unroll
    for (int r = 0; r < 16; ++r) {
        const int ql = (r & 3) + 8 * (r >> 2) + 4 * h;
        const float lv = __shfl(linv, ql, 64);
        const int row = b * SEQ + q0b + wid * 32 + ql;
        unsigned short* orow = attn + (size_t)row * HIDDEN + hh * HDIM;
        orow[l31] = f2bf(acc0[r] * lv);
        orow[32 + l31] = f2bf(acc1[r] * lv);
        if (l31 < 16) orow[64 + l31] = f2bf(acc2[r] * lv);
    }
}

extern "C" void kernel_launch(void* const* d_in, const int* in_sizes, int n_in,
                              void* d_out, int out_size, void* d_ws, size_t ws_size,
                              hipStream_t stream) {
    const int* pos = (const int*)d_in[0];
    const float* hid = (const float*)d_in[1];
    const float* Wqkv = (const float*)d_in[2];
    const float* bqkv = (const float*)d_in[3];
    const float* Wd = (const float*)d_in[4];
    const float* bd = (const float*)d_in[5];
    float* out = (float*)d_out;
    char* ws = (char*)d_ws;

    unsigned short* WqkvT = (unsigned short*)(ws);                // 39,321,600 B
    unsigned short* WdT   = (unsigned short*)(ws + 39321600);     // 13,107,200 B
    unsigned short* Xbf   = (unsigned short*)(ws + 52428800);     // 20,971,520 B
    unsigned short* qkv   = (unsigned short*)(ws + 73400320);     // 62,914,560 B
    unsigned short* Qbuf  = (unsigned short*)(ws + 136314880);    // 25,165,824 B
    unsigned short* Kbuf  = (unsigned short*)(ws + 161480704);    // 25,165,824 B
    unsigned short* Vt    = (unsigned short*)(ws + 186646528);    // 20,971,520 B
    unsigned short* attnb = Xbf;  // Xbf dead after gemm1; reuse for attention output

    cvt_kernel<<<(M_TOK * HIDDEN / 8 + 255) / 256, 256, 0, stream>>>(hid, Xbf, M_TOK * HIDDEN / 8);
    transpose_kernel<<<dim3(N_QKV / 64, HIDDEN / 64), 256, 0, stream>>>(Wqkv, WqkvT, HIDDEN, N_QKV);
    transpose_kernel<<<dim3(HIDDEN / 64, HIDDEN / 64), 256, 0, stream>>>(Wd, WdT, HIDDEN, HIDDEN);
    gemm_bt<1><<<dim3(N_QKV / 128, M_TOK / 128), 256, 0, stream>>>(Xbf, WqkvT, bqkv, qkv,
                                                                   M_TOK, N_QKV, HIDDEN);
    pack_rope_kernel<<<(64 * SEQ) / 256, 256, 0, stream>>>(qkv, pos, Qbuf, Kbuf, Vt);
    flash_kernel<<<dim3(64, 8), 512, 0, stream>>>(Qbuf, Kbuf, Vt, attnb);
    gemm_bt<0><<<dim3(HIDDEN / 128, M_TOK / 128), 256, 0, stream>>>(attnb, WdT, bd, out,
                                                                    M_TOK, HIDDEN, HIDDEN);
}

// Round 7
// 454.652 us; speedup vs baseline: 1.5161x; 1.0744x over previous
//
#include <hip/hip_runtime.h>

#define HIDDEN 2560
#define NHEADS 32
#define HDIM 80
#define DPAD 96
#define SEQ 2048
#define M_TOK 4096
#define N_QKV 7680
#define ATT_SCALE 0.11180339887498949f  // 80^-0.5

typedef __attribute__((ext_vector_type(4))) float f32x4;
typedef __attribute__((ext_vector_type(16))) float f32x16;
typedef __attribute__((ext_vector_type(4))) int i32x4;
typedef __attribute__((ext_vector_type(8))) short bf16x8;
typedef __attribute__((ext_vector_type(8))) unsigned short ushort8;

#define BAR() asm volatile("s_barrier" ::: "memory")

__device__ __forceinline__ unsigned short f2bf(float f) {
    unsigned int u = __float_as_uint(f);
    u += 0x7FFFu + ((u >> 16) & 1u);
    return (unsigned short)(u >> 16);
}
__device__ __forceinline__ float bf2f(unsigned short h) {
    return __uint_as_float(((unsigned int)h) << 16);
}

__device__ __forceinline__ void async_copy16(unsigned short* lds, const unsigned short* g) {
    __builtin_amdgcn_global_load_lds((const __attribute__((address_space(1))) void*)g,
                                     (__attribute__((address_space(3))) void*)lds, 16, 0, 0);
}

__device__ __forceinline__ int cvt_pk_bf16(float lo, float hi) {
    int d;
    asm("v_cvt_pk_bf16_f32 %0, %1, %2" : "=v"(d) : "v"(lo), "v"(hi));
    return d;
}

// ---------------- fp32 -> bf16 convert (8 elems/thread) ----------------
__global__ __launch_bounds__(256) void cvt_kernel(const float* __restrict__ in,
                                                  unsigned short* __restrict__ out, int n8) {
    int i = blockIdx.x * 256 + threadIdx.x;
    if (i >= n8) return;
    const float4* p = (const float4*)in + (size_t)i * 2;
    float4 a = p[0], b = p[1];
    ushort8 o;
    o[0] = f2bf(a.x); o[1] = f2bf(a.y); o[2] = f2bf(a.z); o[3] = f2bf(a.w);
    o[4] = f2bf(b.x); o[5] = f2bf(b.y); o[6] = f2bf(b.z); o[7] = f2bf(b.w);
    *((ushort8*)out + i) = o;
}

// ---------------- fp32 [R][C] -> bf16 [C][R] transpose ----------------
__global__ __launch_bounds__(256) void transpose_kernel(const float* __restrict__ in,
                                                        unsigned short* __restrict__ out,
                                                        int R, int C) {
    __shared__ unsigned short tile[64][66];
    const int r0 = blockIdx.y * 64, c0 = blockIdx.x * 64;
    const int t = threadIdx.x;
#pragma unroll
    for (int rep = 0; rep < 16; ++rep) {
        int idx = rep * 256 + t;
        int i = idx >> 6, j = idx & 63;
        tile[i][j] = f2bf(in[(size_t)(r0 + i) * C + (c0 + j)]);
    }
    __syncthreads();
#pragma unroll
    for (int rep = 0; rep < 16; ++rep) {
        int idx = rep * 256 + t;
        int j = idx >> 6, i = idx & 63;
        out[(size_t)(c0 + j) * R + (r0 + i)] = tile[i][j];
    }
}

// ---------------- 256x256 counted-vmcnt phased GEMM ----------------
// C[M][N] = A[M][K] * Bt[N][K]^T + bias. 512 threads (8 waves, 2M x 4N),
// BK=64, 2-tile double-buffered LDS (128 KiB), global_load_lds staging with
// both-sides swizzle (rule #21). Schedule: per tile {vmcnt(8); barrier;
// 4 phases of [ds_read quad + setprio MFMA x16 + s_barrier]; stage T+2}.
// vmcnt BEFORE barrier => every wave confirmed its own loads landed =>
// union over waves = whole tile landed (no cross-wave FIFO assumption).
template <int OUT_BF16>
__global__ __launch_bounds__(512, 2) void gemm256(const unsigned short* __restrict__ A,
                                                  const unsigned short* __restrict__ Bt,
                                                  const float* __restrict__ bias,
                                                  void* __restrict__ C,
                                                  int M, int N, int K) {
    __shared__ __align__(16) unsigned short Alds[2][256 * 64];
    __shared__ __align__(16) unsigned short Blds[2][256 * 64];
    const int t = threadIdx.x;
    const int lane = t & 63, wid = t >> 6;
    const int wm = wid >> 2, wn = wid & 3;
    const int l15 = lane & 15, lhi = lane >> 4;

    // XCD-aware bijective swizzle (gridDim.x % 8 == 0); M fastest (16 M-tiles)
    // so consecutive wg on one XCD share the B column-panel (1.25 MB < 4 MB L2).
    const int cpx = (int)gridDim.x >> 3;
    const int wg = ((int)blockIdx.x % 8) * cpx + ((int)blockIdx.x >> 3);
    const int bm = (wg & 15) * 256;
    const int bn = (wg >> 4) * 256;

    // staging constants: tile = 2048 x 16B chunks, 4 per thread; source column
    // pre-swizzled so LDS (row,c) holds global (row, c^(row&7))  [rule #21]
    int srow[4], scol[4];
#pragma unroll
    for (int c = 0; c < 4; ++c) {
        int idx = t + c * 512;
        srow[c] = idx >> 3;
        scol[c] = ((idx & 7) ^ (srow[c] & 7)) * 8;
    }
    const unsigned short* Abase = A + (size_t)bm * K;
    const unsigned short* Bbase = Bt + (size_t)bn * K;
    const int NT = K >> 6;

    auto stage = [&](int kt, int b) {
        const int k0 = kt << 6;
#pragma unroll
        for (int c = 0; c < 4; ++c)
            async_copy16(Alds[b] + (t + c * 512) * 8,
                         Abase + (size_t)srow[c] * K + k0 + scol[c]);
#pragma unroll
        for (int c = 0; c < 4; ++c)
            async_copy16(Blds[b] + (t + c * 512) * 8,
                         Bbase + (size_t)srow[c] * K + k0 + scol[c]);
    };

    f32x4 acc[8][4] = {};
    const int arow = wm * 128 + l15;
    const int brow = wn * 64 + l15;
    const int r7 = l15 & 7;

    stage(0, 0);
    stage(1, 1);

    for (int T = 0; T < NT; ++T) {
        const int b = T & 1;
        if (T < NT - 1) asm volatile("s_waitcnt vmcnt(8)" ::: "memory");
        else            asm volatile("s_waitcnt vmcnt(0)" ::: "memory");
        BAR();  // all waves' tile-T chunks landed
        bf16x8 bq[4][2];
#pragma unroll
        for (int j = 0; j < 4; ++j)
#pragma unroll
            for (int kk = 0; kk < 2; ++kk)
                bq[j][kk] = *(const bf16x8*)(Blds[b] + (brow + j * 16) * 64 +
                                             (((kk * 4 + lhi) ^ r7) * 8));
#pragma unroll
        for (int q = 0; q < 4; ++q) {
            bf16x8 af2[2][2];
#pragma unroll
            for (int ii = 0; ii < 2; ++ii)
#pragma unroll
                for (int kk = 0; kk < 2; ++kk)
                    af2[ii][kk] = *(const bf16x8*)(Alds[b] + (arow + (q * 2 + ii) * 16) * 64 +
                                                   (((kk * 4 + lhi) ^ r7) * 8));
            __builtin_amdgcn_s_setprio(1);
#pragma unroll
            for (int ii = 0; ii < 2; ++ii)
#pragma unroll
                for (int j = 0; j < 4; ++j)
#pragma unroll
                    for (int kk = 0; kk < 2; ++kk)
                        acc[q * 2 + ii][j] = __builtin_amdgcn_mfma_f32_16x16x32_bf16(
                            af2[ii][kk], bq[j][kk], acc[q * 2 + ii][j], 0, 0, 0);
            __builtin_amdgcn_s_setprio(0);
            BAR();  // phase boundary; last one = all waves done reading buf b
        }
        if (T + 2 < NT) stage(T + 2, b);
    }

#pragma unroll
    for (int j = 0; j < 4; ++j) {
        const int col = bn + wn * 64 + j * 16 + l15;
        const float bv = bias[col];
#pragma unroll
        for (int i = 0; i < 8; ++i) {
            const int row0 = bm + wm * 128 + i * 16 + lhi * 4;
#pragma unroll
            for (int r = 0; r < 4; ++r) {
                float v = acc[i][j][r] + bv;
                if (OUT_BF16)
                    ((unsigned short*)C)[(size_t)(row0 + r) * N + col] = f2bf(v);
                else
                    ((float*)C)[(size_t)(row0 + r) * N + col] = v;
            }
        }
    }
}

// ---------------- pack qkv -> Q (rope+scale, pad 96), K (rope, pad 96), Vt ----------------
__global__ __launch_bounds__(256) void pack_rope_kernel(const unsigned short* __restrict__ qkv,
                                                        const int* __restrict__ pos_ids,
                                                        unsigned short* __restrict__ Qb,
                                                        unsigned short* __restrict__ Kb,
                                                        unsigned short* __restrict__ Vt) {
    int g = blockIdx.x * 256 + threadIdx.x;  // (b*32+h)*2048 + s
    int s = g & (SEQ - 1);
    int bh = g >> 11;
    int b = bh >> 5;
    int h = bh & 31;
    int m = b * SEQ + s;
    const unsigned short* base = qkv + (size_t)m * N_QKV + h * HDIM;
    unsigned short* Qrow = Qb + ((size_t)bh * SEQ + s) * DPAD;
    unsigned short* Krow = Kb + ((size_t)bh * SEQ + s) * DPAD;
    unsigned short* Vcol = Vt + (size_t)bh * HDIM * SEQ + s;

    float pos = (float)pos_ids[m];
    float qv[32], kv[32];
#pragma unroll
    for (int c = 0; c < 4; ++c) {
        ushort8 qc = *(const ushort8*)(base + c * 8);
        ushort8 kc = *(const ushort8*)(base + HIDDEN + c * 8);
#pragma unroll
        for (int j = 0; j < 8; ++j) {
            qv[c * 8 + j] = bf2f(qc[j]);
            kv[c * 8 + j] = bf2f(kc[j]);
        }
    }
#pragma unroll
    for (int d = 0; d < 16; ++d) {
        float inv = __expf(-(float)d * 0.5756462732485115f);  // ln(10000)/16
        float ang = pos * inv;
        float sn, cs;
        __sincosf(ang, &sn, &cs);
        float qcs = cs * ATT_SCALE, qsn = sn * ATT_SCALE;  // fold softmax scale into Q
        float x1 = qv[d], x2 = qv[d + 16];
        qv[d] = x1 * qcs - x2 * qsn;
        qv[d + 16] = x2 * qcs + x1 * qsn;
        x1 = kv[d]; x2 = kv[d + 16];
        kv[d] = x1 * cs - x2 * sn;
        kv[d + 16] = x2 * cs + x1 * sn;
    }
#pragma unroll
    for (int c = 0; c < 4; ++c) {
        ushort8 qo, ko;
#pragma unroll
        for (int j = 0; j < 8; ++j) {
            qo[j] = f2bf(qv[c * 8 + j]);
            ko[j] = f2bf(kv[c * 8 + j]);
        }
        *(ushort8*)(Qrow + c * 8) = qo;
        *(ushort8*)(Krow + c * 8) = ko;
    }
#pragma unroll
    for (int c = 4; c < 10; ++c) {
        ushort8 qc = *(const ushort8*)(base + c * 8);
        ushort8 qo;
#pragma unroll
        for (int j = 0; j < 8; ++j) qo[j] = f2bf(bf2f(qc[j]) * ATT_SCALE);
        *(ushort8*)(Qrow + c * 8) = qo;
        *(ushort8*)(Krow + c * 8) = *(const ushort8*)(base + HIDDEN + c * 8);
    }
    ushort8 z = {0, 0, 0, 0, 0, 0, 0, 0};
    *(ushort8*)(Qrow + 80) = z;
    *(ushort8*)(Qrow + 88) = z;
    *(ushort8*)(Krow + 80) = z;
    *(ushort8*)(Krow + 88) = z;
#pragma unroll
    for (int d = 0; d < HDIM; ++d) Vcol[(size_t)d * SEQ] = base[2 * HIDDEN + d];
}

// ---------------- causal flash attention v3: swapped QK^T, in-register softmax ----------------
// 8 waves x 32 q-rows (QBLK=256), KVBLK=64, mfma 32x32x16.
// S^T = mfma(K, Q): lane holds its q-row's scores lane-locally.
// K LDS [64][128] xor-swz; V LDS [96][64] xor-swz (rows 80..95 zeroed once).
// P h-half exchange via __shfl_xor (unambiguous semantics); permlane A/B deferred.
__global__ __launch_bounds__(512) void flash_kernel(const unsigned short* __restrict__ Qb,
                                                    const unsigned short* __restrict__ Kb,
                                                    const unsigned short* __restrict__ Vt,
                                                    unsigned short* __restrict__ attn) {
    __shared__ __align__(16) unsigned short Klds[64 * 128];
    __shared__ __align__(16) unsigned short Vlds[96 * 64];

    const int bh = blockIdx.x;
    const int qb = 7 - (int)blockIdx.y;  // heavy blocks dispatch first
    const int q0b = qb * 256;
    const int nkt = 4 * qb + 4;
    const int t = threadIdx.x;
    const int lane = t & 63, wid = t >> 6;
    const int l31 = lane & 31, h = lane >> 5, l7 = lane & 7;
    const int q0w = q0b + wid * 32;
    const int swz = l7 << 3;  // xor on shorts-offset (== (row&7)<<4 bytes)

    const unsigned short* Kbase = Kb + (size_t)bh * SEQ * DPAD;
    const unsigned short* Vbase = Vt + (size_t)bh * HDIM * SEQ;

    // Q B-frags: lane holds q-row (l31), d-slice h*8 per 16-d chunk
    bf16x8 qf[6];
    {
        const unsigned short* Qrow = Qb + ((size_t)bh * SEQ + q0w + l31) * DPAD + h * 8;
#pragma unroll
        for (int dc = 0; dc < 6; ++dc) qf[dc] = *(const bf16x8*)(Qrow + dc * 16);
    }

    // zero V pad rows 80..95 once (512 ints == 16 rows * 128B)
    ((int*)Vlds)[2560 + t] = 0;

    f32x16 acc0 = {}, acc1 = {}, acc2 = {};
    float mrow = -1e30f, lrow = 0.f;

    // staging constants: K 768x16B chunks (global-linear), V 640x16B chunks
    const int kidx1 = 512 + t;
    const int kr0 = t / 12, kc0 = t % 12;
    const int kr1 = kidx1 / 12, kc1 = kidx1 % 12;
    const int vr0 = t >> 3, vc0 = t & 7;
    const int vr1 = (512 + t) >> 3, vc1 = t & 7;
    const int kd0 = kr0 * 128 + ((kc0 * 8) ^ ((kr0 & 7) << 3));
    const int kd1 = kr1 * 128 + ((kc1 * 8) ^ ((kr1 & 7) << 3));
    const int vd0 = vr0 * 64 + ((vc0 * 8) ^ ((vr0 & 7) << 3));
    const int vd1 = vr1 * 64 + ((vc1 * 8) ^ ((vr1 & 7) << 3));

    ushort8 kreg0, kreg1, vreg0, vreg1;
    kreg0 = *(const ushort8*)(Kbase + (size_t)t * 8);
    if (t < 256) kreg1 = *(const ushort8*)(Kbase + (size_t)kidx1 * 8);
    vreg0 = *(const ushort8*)(Vbase + (size_t)vr0 * SEQ + vc0 * 8);
    if (t < 128) vreg1 = *(const ushort8*)(Vbase + (size_t)vr1 * SEQ + vc1 * 8);

    for (int kt = 0; kt < nkt; ++kt) {
        const int k0 = kt * 64;
        __syncthreads();  // prev tile's LDS reads done
        *(ushort8*)(Klds + kd0) = kreg0;
        if (t < 256) *(ushort8*)(Klds + kd1) = kreg1;
        *(ushort8*)(Vlds + vd0) = vreg0;
        if (t < 128) *(ushort8*)(Vlds + vd1) = vreg1;
        __syncthreads();  // tile visible
        if (kt + 1 < nkt) {  // prefetch next tile; hides under compute
            const int kn = k0 + 64;
            kreg0 = *(const ushort8*)(Kbase + (size_t)kn * DPAD + (size_t)t * 8);
            if (t < 256) kreg1 = *(const ushort8*)(Kbase + (size_t)kn * DPAD + (size_t)kidx1 * 8);
            vreg0 = *(const ushort8*)(Vbase + (size_t)vr0 * SEQ + kn + vc0 * 8);
            if (t < 128) vreg1 = *(const ushort8*)(Vbase + (size_t)vr1 * SEQ + kn + vc1 * 8);
        }
        if (k0 > q0w + 31) continue;  // wave fully masked (barriers already passed)

        // ---- QK^T swapped: S^T[k][q] ----
        f32x16 s0 = {}, s1 = {};
        __builtin_amdgcn_s_setprio(1);
#pragma unroll
        for (int dc = 0; dc < 6; ++dc) {
            const int co = (dc * 16 + h * 8) ^ swz;
            bf16x8 ka = *(const bf16x8*)(Klds + l31 * 128 + co);
            bf16x8 kb2 = *(const bf16x8*)(Klds + (32 + l31) * 128 + co);
            s0 = __builtin_amdgcn_mfma_f32_32x32x16_bf16(ka, qf[dc], s0, 0, 0, 0);
            s1 = __builtin_amdgcn_mfma_f32_32x32x16_bf16(kb2, qf[dc], s1, 0, 0, 0);
        }
        __builtin_amdgcn_s_setprio(0);

        const int qg = q0w + l31;
        if (k0 + 63 > q0w) {  // boundary tile: causal mask
#pragma unroll
            for (int r = 0; r < 16; ++r) {
                const int kg = k0 + (r & 3) + 8 * (r >> 2) + 4 * h;
                if (kg > qg) s0[r] = -2e30f;
                if (kg + 32 > qg) s1[r] = -2e30f;
            }
        }
        // ---- in-register online softmax (row = lane-local) ----
        float pmax = s0[0];
#pragma unroll
        for (int r = 1; r < 16; ++r) pmax = fmaxf(pmax, s0[r]);
#pragma unroll
        for (int r = 0; r < 16; ++r) pmax = fmaxf(pmax, s1[r]);
        pmax = fmaxf(pmax, __shfl_xor(pmax, 32, 64));  // combine partner half (same q-row)
        if (!__all(pmax <= mrow + 8.0f)) {  // defer-max (exact)
            float mnew = fmaxf(mrow, pmax);
            float scl = __expf(mrow - mnew);
            mrow = mnew;
            lrow *= scl;
#pragma unroll
            for (int r = 0; r < 16; ++r) {
                float sq = __shfl(scl, (r & 3) + 8 * (r >> 2) + 4 * h, 64);
                acc0[r] *= sq; acc1[r] *= sq; acc2[r] *= sq;
            }
        }
        float ps = 0.f;
#pragma unroll
        for (int r = 0; r < 16; ++r) { s0[r] = __expf(s0[r] - mrow); ps += s0[r]; }
#pragma unroll
        for (int r = 0; r < 16; ++r) { s1[r] = __expf(s1[r] - mrow); ps += s1[r]; }
        lrow += ps + __shfl_xor(ps, 32, 64);  // own + partner half
        // ---- P pack to A-frags: cvt_pk + shfl_xor half-exchange ----
        i32x4 af[2][2];
#pragma unroll
        for (int ks = 0; ks < 2; ++ks) {
            const f32x16& sv = ks ? s1 : s0;
            int pk0[2], pk1[2], pk2[2], pk3[2];
#pragma unroll
            for (int i = 0; i < 2; ++i) {
                pk0[i] = cvt_pk_bf16(sv[2 * i], sv[2 * i + 1]);
                pk1[i] = cvt_pk_bf16(sv[4 + 2 * i], sv[5 + 2 * i]);
                pk2[i] = cvt_pk_bf16(sv[8 + 2 * i], sv[9 + 2 * i]);
                pk3[i] = cvt_pk_bf16(sv[12 + 2 * i], sv[13 + 2 * i]);
            }
#pragma unroll
            for (int i = 0; i < 2; ++i) {
                const int o0 = __shfl_xor(pk0[i], 32, 64);
                const int o1 = __shfl_xor(pk1[i], 32, 64);
                af[ks][0][i]     = h ? o1     : pk0[i];
                af[ks][0][2 + i] = h ? pk1[i] : o0;
                const int o2 = __shfl_xor(pk2[i], 32, 64);
                const int o3 = __shfl_xor(pk3[i], 32, 64);
                af[ks][1][i]     = h ? o3     : pk2[i];
                af[ks][1][2 + i] = h ? pk3[i] : o2;
            }
        }
        // ---- PV: O[q][d] ----
        __builtin_amdgcn_s_setprio(1);
#pragma unroll
        for (int ds = 0; ds < 3; ++ds) {
            f32x16& ac = ds == 0 ? acc0 : (ds == 1 ? acc1 : acc2);
            const int vrow = (ds * 32 + l31) * 64;
#pragma unroll
            for (int ks = 0; ks < 2; ++ks)
#pragma unroll
                for (int kh = 0; kh < 2; ++kh) {
                    bf16x8 vb = *(const bf16x8*)(Vlds + vrow + ((ks * 32 + kh * 16 + h * 8) ^ swz));
                    bf16x8 pa = __builtin_bit_cast(bf16x8, af[ks][kh]);
                    ac = __builtin_amdgcn_mfma_f32_32x32x16_bf16(pa, vb, ac, 0, 0, 0);
                }
        }
        __builtin_amdgcn_s_setprio(0);
    }

    // ---- epilogue ----
    const int hh = bh & 31, b = bh >> 5;
    const float linv = 1.0f / lrow;
#pragma unroll
    for (int r = 0; r < 16; ++r) {
        const int ql = (r & 3) + 8 * (r >> 2) + 4 * h;
        const float lv = __shfl(linv, ql, 64);
        const int row = b * SEQ + q0b + wid * 32 + ql;
        unsigned short* orow = attn + (size_t)row * HIDDEN + hh * HDIM;
        orow[l31] = f2bf(acc0[r] * lv);
        orow[32 + l31] = f2bf(acc1[r] * lv);
        if (l31 < 16) orow[64 + l31] = f2bf(acc2[r] * lv);
    }
}

extern "C" void kernel_launch(void* const* d_in, const int* in_sizes, int n_in,
                              void* d_out, int out_size, void* d_ws, size_t ws_size,
                              hipStream_t stream) {
    const int* pos = (const int*)d_in[0];
    const float* hid = (const float*)d_in[1];
    const float* Wqkv = (const float*)d_in[2];
    const float* bqkv = (const float*)d_in[3];
    const float* Wd = (const float*)d_in[4];
    const float* bd = (const float*)d_in[5];
    float* out = (float*)d_out;
    char* ws = (char*)d_ws;

    unsigned short* WqkvT = (unsigned short*)(ws);                // 39,321,600 B
    unsigned short* WdT   = (unsigned short*)(ws + 39321600);     // 13,107,200 B
    unsigned short* Xbf   = (unsigned short*)(ws + 52428800);     // 20,971,520 B
    unsigned short* qkv   = (unsigned short*)(ws + 73400320);     // 62,914,560 B
    unsigned short* Qbuf  = (unsigned short*)(ws + 136314880);    // 25,165,824 B
    unsigned short* Kbuf  = (unsigned short*)(ws + 161480704);    // 25,165,824 B
    unsigned short* Vt    = (unsigned short*)(ws + 186646528);    // 20,971,520 B
    unsigned short* attnb = Xbf;  // Xbf dead after gemm1; reuse for attention output

    cvt_kernel<<<(M_TOK * HIDDEN / 8 + 255) / 256, 256, 0, stream>>>(hid, Xbf, M_TOK * HIDDEN / 8);
    transpose_kernel<<<dim3(N_QKV / 64, HIDDEN / 64), 256, 0, stream>>>(Wqkv, WqkvT, HIDDEN, N_QKV);
    transpose_kernel<<<dim3(HIDDEN / 64, HIDDEN / 64), 256, 0, stream>>>(Wd, WdT, HIDDEN, HIDDEN);
    gemm256<1><<<(M_TOK / 256) * (N_QKV / 256), 512, 0, stream>>>(Xbf, WqkvT, bqkv, qkv,
                                                                  M_TOK, N_QKV, HIDDEN);
    pack_rope_kernel<<<(64 * SEQ) / 256, 256, 0, stream>>>(qkv, pos, Qbuf, Kbuf, Vt);
    flash_kernel<<<dim3(64, 8), 512, 0, stream>>>(Qbuf, Kbuf, Vt, attnb);
    gemm256<0><<<(M_TOK / 256) * (HIDDEN / 256), 512, 0, stream>>>(attnb, WdT, bd, out,
                                                                   M_TOK, HIDDEN, HIDDEN);
}

// Round 8
// 388.224 us; speedup vs baseline: 1.7756x; 1.1711x over previous
//
#include <hip/hip_runtime.h>

#define HIDDEN 2560
#define NHEADS 32
#define HDIM 80
#define DPAD 96
#define SEQ 2048
#define M_TOK 4096
#define N_QKV 7680
#define ATT_SCALE 0.11180339887498949f  // 80^-0.5

typedef __attribute__((ext_vector_type(4))) float f32x4;
typedef __attribute__((ext_vector_type(16))) float f32x16;
typedef __attribute__((ext_vector_type(4))) int i32x4;
typedef __attribute__((ext_vector_type(8))) short bf16x8;
typedef __attribute__((ext_vector_type(8))) unsigned short ushort8;

#define BAR() asm volatile("s_barrier" ::: "memory")

__device__ __forceinline__ unsigned short f2bf(float f) {
    unsigned int u = __float_as_uint(f);
    u += 0x7FFFu + ((u >> 16) & 1u);
    return (unsigned short)(u >> 16);
}
__device__ __forceinline__ float bf2f(unsigned short h) {
    return __uint_as_float(((unsigned int)h) << 16);
}

__device__ __forceinline__ void async_copy16(unsigned short* lds, const unsigned short* g) {
    __builtin_amdgcn_global_load_lds((const __attribute__((address_space(1))) void*)g,
                                     (__attribute__((address_space(3))) void*)lds, 16, 0, 0);
}

__device__ __forceinline__ int cvt_pk_bf16(float lo, float hi) {
    int d;
    asm("v_cvt_pk_bf16_f32 %0, %1, %2" : "=v"(d) : "v"(lo), "v"(hi));
    return d;
}

// ---------------- fp32 -> bf16 convert (8 elems/thread) ----------------
__global__ __launch_bounds__(256) void cvt_kernel(const float* __restrict__ in,
                                                  unsigned short* __restrict__ out, int n8) {
    int i = blockIdx.x * 256 + threadIdx.x;
    if (i >= n8) return;
    const float4* p = (const float4*)in + (size_t)i * 2;
    float4 a = p[0], b = p[1];
    ushort8 o;
    o[0] = f2bf(a.x); o[1] = f2bf(a.y); o[2] = f2bf(a.z); o[3] = f2bf(a.w);
    o[4] = f2bf(b.x); o[5] = f2bf(b.y); o[6] = f2bf(b.z); o[7] = f2bf(b.w);
    *((ushort8*)out + i) = o;
}

// ---------------- fp32 [R][C] -> bf16 [C][R] transpose ----------------
__global__ __launch_bounds__(256) void transpose_kernel(const float* __restrict__ in,
                                                        unsigned short* __restrict__ out,
                                                        int R, int C) {
    __shared__ unsigned short tile[64][66];
    const int r0 = blockIdx.y * 64, c0 = blockIdx.x * 64;
    const int t = threadIdx.x;
#pragma unroll
    for (int rep = 0; rep < 16; ++rep) {
        int idx = rep * 256 + t;
        int i = idx >> 6, j = idx & 63;
        tile[i][j] = f2bf(in[(size_t)(r0 + i) * C + (c0 + j)]);
    }
    __syncthreads();
#pragma unroll
    for (int rep = 0; rep < 16; ++rep) {
        int idx = rep * 256 + t;
        int j = idx >> 6, i = idx & 63;
        out[(size_t)(c0 + j) * R + (r0 + i)] = tile[i][j];
    }
}

// ---------------- 256x256 fine-interleaved GEMM, K=32 half-tile pipeline ----------------
// C[M][N] = A[M][K]*Bt[N][K]^T + bias. 512 thr (8 waves 2Mx4N), period = K-32 strip.
// LDS: 4 slots x (A[256][32]+B[256][32]) = 128 KiB; slot(j)=j&3.
// Period j: vmcnt(8); BAR; {stage 2 A-loads of H_{j+3}; ds_read B(4)+A(4); 16 MFMA}
//           {stage 2 B-loads of H_{j+3}; ds_read A(4); 16 MFMA}.
// H_{j+3} goes to slot (j+3)&3 = (j-1)&3, freed at end of period j-1 (BAR-protected).
// Cover: staged 3 periods before consumption. vmcnt(8): outstanding at period top =
// H_{j+1},H_{j+2} (8) + H_j-if-unlanded -> drains H_j; per-wave vmcnt->BAR->union.
// Swizzle: 4 chunks/row, phys = log ^ ((row>>1)&3); rows 0-15 hit 8 bank-groups
// 2-way (free). Source column pre-swizzled to match (both-sides rule).
template <int OUT_BF16>
__global__ __launch_bounds__(512, 2) void gemm256(const unsigned short* __restrict__ A,
                                                  const unsigned short* __restrict__ Bt,
                                                  const float* __restrict__ bias,
                                                  void* __restrict__ C,
                                                  int M, int N, int K) {
    __shared__ __align__(16) unsigned short S[4][16384];  // [slot]: A 8192 | B 8192
    const int t = threadIdx.x;
    const int lane = t & 63, wid = t >> 6;
    const int wm = wid >> 2, wn = wid & 3;
    const int l15 = lane & 15, lhi = lane >> 4;

    const int cpx = (int)gridDim.x >> 3;
    const int wg = ((int)blockIdx.x % 8) * cpx + ((int)blockIdx.x >> 3);
    const int bm = (wg & 15) * 256;
    const int bn = (wg >> 4) * 256;

    int srow[2], scol[2];
#pragma unroll
    for (int c = 0; c < 2; ++c) {
        int idx = t + c * 512;
        srow[c] = idx >> 2;
        scol[c] = ((idx & 3) ^ ((srow[c] >> 1) & 3)) * 8;  // pre-swizzled source chunk
    }
    const unsigned short* Abase = A + (size_t)bm * K;
    const unsigned short* Bbase = Bt + (size_t)bn * K;
    const int NT = K >> 6;  // 64-K tiles; periods = 2*NT

    // fragment LDS offsets (within a slot half), rows: A wm*128+i*16+l15, B wn*64+f*16+l15
    int aoff[8], boff[4];
#pragma unroll
    for (int i = 0; i < 8; ++i) {
        int r = wm * 128 + i * 16 + l15;
        aoff[i] = r * 32 + ((lhi ^ ((r >> 1) & 3)) * 8);
    }
#pragma unroll
    for (int f = 0; f < 4; ++f) {
        int r = wn * 64 + f * 16 + l15;
        boff[f] = 8192 + r * 32 + ((lhi ^ ((r >> 1) & 3)) * 8);
    }

    f32x4 acc[8][4] = {};

#define STAGE_A(J) { const int j_ = (J); unsigned short* d = &S[j_ & 3][0];            \
    _Pragma("unroll")                                                                  \
    for (int c = 0; c < 2; ++c)                                                        \
        async_copy16(d + (t + c * 512) * 8,                                            \
                     Abase + (size_t)srow[c] * K + j_ * 32 + scol[c]); }
#define STAGE_B(J) { const int j_ = (J); unsigned short* d = &S[j_ & 3][8192];         \
    _Pragma("unroll")                                                                  \
    for (int c = 0; c < 2; ++c)                                                        \
        async_copy16(d + (t + c * 512) * 8,                                            \
                     Bbase + (size_t)srow[c] * K + j_ * 32 + scol[c]); }

#define PERIOD(J, VM, DOSTAGE) {                                                       \
    const int jp_ = (J);                                                               \
    asm volatile("s_waitcnt vmcnt(" #VM ")" ::: "memory");                             \
    BAR();                                                                             \
    const unsigned short* sl = &S[jp_ & 3][0];                                         \
    if (DOSTAGE) STAGE_A(jp_ + 3);                                                     \
    bf16x8 bq[4], afr[4];                                                              \
    _Pragma("unroll")                                                                  \
    for (int f = 0; f < 4; ++f) bq[f] = *(const bf16x8*)(sl + boff[f]);                \
    _Pragma("unroll")                                                                  \
    for (int i = 0; i < 4; ++i) afr[i] = *(const bf16x8*)(sl + aoff[i]);               \
    __builtin_amdgcn_s_setprio(1);                                                     \
    _Pragma("unroll")                                                                  \
    for (int i = 0; i < 4; ++i)                                                        \
        _Pragma("unroll")                                                              \
        for (int f = 0; f < 4; ++f)                                                    \
            acc[i][f] = __builtin_amdgcn_mfma_f32_16x16x32_bf16(afr[i], bq[f],         \
                                                                acc[i][f], 0, 0, 0);   \
    __builtin_amdgcn_s_setprio(0);                                                     \
    if (DOSTAGE) STAGE_B(jp_ + 3);                                                     \
    _Pragma("unroll")                                                                  \
    for (int i = 0; i < 4; ++i) afr[i] = *(const bf16x8*)(sl + aoff[4 + i]);           \
    __builtin_amdgcn_s_setprio(1);                                                     \
    _Pragma("unroll")                                                                  \
    for (int i = 0; i < 4; ++i)                                                        \
        _Pragma("unroll")                                                              \
        for (int f = 0; f < 4; ++f)                                                    \
            acc[4 + i][f] = __builtin_amdgcn_mfma_f32_16x16x32_bf16(afr[i], bq[f],     \
                                                                    acc[4 + i][f],     \
                                                                    0, 0, 0);          \
    __builtin_amdgcn_s_setprio(0); }

    // prologue: stage periods 0,1,2
    STAGE_A(0); STAGE_B(0);
    STAGE_A(1); STAGE_B(1);
    STAGE_A(2); STAGE_B(2);

    for (int T = 0; T < NT - 2; ++T) {
        PERIOD(2 * T, 8, 1);
        PERIOD(2 * T + 1, 8, 1);
    }
    PERIOD(2 * NT - 4, 8, 1);   // stages H_{2NT-1}
    PERIOD(2 * NT - 3, 8, 0);
    PERIOD(2 * NT - 2, 4, 0);
    PERIOD(2 * NT - 1, 0, 0);

#undef PERIOD
#undef STAGE_A
#undef STAGE_B

#pragma unroll
    for (int f = 0; f < 4; ++f) {
        const int col = bn + wn * 64 + f * 16 + l15;
        const float bv = bias[col];
#pragma unroll
        for (int i = 0; i < 8; ++i) {
            const int row0 = bm + wm * 128 + i * 16 + lhi * 4;
#pragma unroll
            for (int r = 0; r < 4; ++r) {
                float v = acc[i][f][r] + bv;
                if (OUT_BF16)
                    ((unsigned short*)C)[(size_t)(row0 + r) * N + col] = f2bf(v);
                else
                    ((float*)C)[(size_t)(row0 + r) * N + col] = v;
            }
        }
    }
}

// ---------------- pack qkv -> Q (rope+scale, pad 96), K (rope, pad 96), Vt ----------------
__global__ __launch_bounds__(256) void pack_rope_kernel(const unsigned short* __restrict__ qkv,
                                                        const int* __restrict__ pos_ids,
                                                        unsigned short* __restrict__ Qb,
                                                        unsigned short* __restrict__ Kb,
                                                        unsigned short* __restrict__ Vt) {
    int g = blockIdx.x * 256 + threadIdx.x;  // (b*32+h)*2048 + s
    int s = g & (SEQ - 1);
    int bh = g >> 11;
    int b = bh >> 5;
    int h = bh & 31;
    int m = b * SEQ + s;
    const unsigned short* base = qkv + (size_t)m * N_QKV + h * HDIM;
    unsigned short* Qrow = Qb + ((size_t)bh * SEQ + s) * DPAD;
    unsigned short* Krow = Kb + ((size_t)bh * SEQ + s) * DPAD;
    unsigned short* Vcol = Vt + (size_t)bh * HDIM * SEQ + s;

    float pos = (float)pos_ids[m];
    float qv[32], kv[32];
#pragma unroll
    for (int c = 0; c < 4; ++c) {
        ushort8 qc = *(const ushort8*)(base + c * 8);
        ushort8 kc = *(const ushort8*)(base + HIDDEN + c * 8);
#pragma unroll
        for (int j = 0; j < 8; ++j) {
            qv[c * 8 + j] = bf2f(qc[j]);
            kv[c * 8 + j] = bf2f(kc[j]);
        }
    }
#pragma unroll
    for (int d = 0; d < 16; ++d) {
        float inv = __expf(-(float)d * 0.5756462732485115f);  // ln(10000)/16
        float ang = pos * inv;
        float sn, cs;
        __sincosf(ang, &sn, &cs);
        float qcs = cs * ATT_SCALE, qsn = sn * ATT_SCALE;  // fold softmax scale into Q
        float x1 = qv[d], x2 = qv[d + 16];
        qv[d] = x1 * qcs - x2 * qsn;
        qv[d + 16] = x2 * qcs + x1 * qsn;
        x1 = kv[d]; x2 = kv[d + 16];
        kv[d] = x1 * cs - x2 * sn;
        kv[d + 16] = x2 * cs + x1 * sn;
    }
#pragma unroll
    for (int c = 0; c < 4; ++c) {
        ushort8 qo, ko;
#pragma unroll
        for (int j = 0; j < 8; ++j) {
            qo[j] = f2bf(qv[c * 8 + j]);
            ko[j] = f2bf(kv[c * 8 + j]);
        }
        *(ushort8*)(Qrow + c * 8) = qo;
        *(ushort8*)(Krow + c * 8) = ko;
    }
#pragma unroll
    for (int c = 4; c < 10; ++c) {
        ushort8 qc = *(const ushort8*)(base + c * 8);
        ushort8 qo;
#pragma unroll
        for (int j = 0; j < 8; ++j) qo[j] = f2bf(bf2f(qc[j]) * ATT_SCALE);
        *(ushort8*)(Qrow + c * 8) = qo;
        *(ushort8*)(Krow + c * 8) = *(const ushort8*)(base + HIDDEN + c * 8);
    }
    ushort8 z = {0, 0, 0, 0, 0, 0, 0, 0};
    *(ushort8*)(Qrow + 80) = z;
    *(ushort8*)(Qrow + 88) = z;
    *(ushort8*)(Krow + 80) = z;
    *(ushort8*)(Krow + 88) = z;
#pragma unroll
    for (int d = 0; d < HDIM; ++d) Vcol[(size_t)d * SEQ] = base[2 * HIDDEN + d];
}

// ---------------- causal flash attention v3: swapped QK^T, in-register softmax ----------------
__global__ __launch_bounds__(512) void flash_kernel(const unsigned short* __restrict__ Qb,
                                                    const unsigned short* __restrict__ Kb,
                                                    const unsigned short* __restrict__ Vt,
                                                    unsigned short* __restrict__ attn) {
    __shared__ __align__(16) unsigned short Klds[64 * 128];
    __shared__ __align__(16) unsigned short Vlds[96 * 64];

    const int bh = blockIdx.x;
    const int qb = 7 - (int)blockIdx.y;  // heavy blocks dispatch first
    const int q0b = qb * 256;
    const int nkt = 4 * qb + 4;
    const int t = threadIdx.x;
    const int lane = t & 63, wid = t >> 6;
    const int l31 = lane & 31, h = lane >> 5, l7 = lane & 7;
    const int q0w = q0b + wid * 32;
    const int swz = l7 << 3;  // xor on shorts-offset (== (row&7)<<4 bytes)

    const unsigned short* Kbase = Kb + (size_t)bh * SEQ * DPAD;
    const unsigned short* Vbase = Vt + (size_t)bh * HDIM * SEQ;

    bf16x8 qf[6];
    {
        const unsigned short* Qrow = Qb + ((size_t)bh * SEQ + q0w + l31) * DPAD + h * 8;
#pragma unroll
        for (int dc = 0; dc < 6; ++dc) qf[dc] = *(const bf16x8*)(Qrow + dc * 16);
    }

    ((int*)Vlds)[2560 + t] = 0;  // zero V pad rows 80..95

    f32x16 acc0 = {}, acc1 = {}, acc2 = {};
    float mrow = -1e30f, lrow = 0.f;

    const int kidx1 = 512 + t;
    const int kr0 = t / 12, kc0 = t % 12;
    const int kr1 = kidx1 / 12, kc1 = kidx1 % 12;
    const int vr0 = t >> 3, vc0 = t & 7;
    const int vr1 = (512 + t) >> 3, vc1 = t & 7;
    const int kd0 = kr0 * 128 + ((kc0 * 8) ^ ((kr0 & 7) << 3));
    const int kd1 = kr1 * 128 + ((kc1 * 8) ^ ((kr1 & 7) << 3));
    const int vd0 = vr0 * 64 + ((vc0 * 8) ^ ((vr0 & 7) << 3));
    const int vd1 = vr1 * 64 + ((vc1 * 8) ^ ((vr1 & 7) << 3));

    ushort8 kreg0, kreg1, vreg0, vreg1;
    kreg0 = *(const ushort8*)(Kbase + (size_t)t * 8);
    if (t < 256) kreg1 = *(const ushort8*)(Kbase + (size_t)kidx1 * 8);
    vreg0 = *(const ushort8*)(Vbase + (size_t)vr0 * SEQ + vc0 * 8);
    if (t < 128) vreg1 = *(const ushort8*)(Vbase + (size_t)vr1 * SEQ + vc1 * 8);

    for (int kt = 0; kt < nkt; ++kt) {
        const int k0 = kt * 64;
        __syncthreads();
        *(ushort8*)(Klds + kd0) = kreg0;
        if (t < 256) *(ushort8*)(Klds + kd1) = kreg1;
        *(ushort8*)(Vlds + vd0) = vreg0;
        if (t < 128) *(ushort8*)(Vlds + vd1) = vreg1;
        __syncthreads();
        if (kt + 1 < nkt) {
            const int kn = k0 + 64;
            kreg0 = *(const ushort8*)(Kbase + (size_t)kn * DPAD + (size_t)t * 8);
            if (t < 256) kreg1 = *(const ushort8*)(Kbase + (size_t)kn * DPAD + (size_t)kidx1 * 8);
            vreg0 = *(const ushort8*)(Vbase + (size_t)vr0 * SEQ + kn + vc0 * 8);
            if (t < 128) vreg1 = *(const ushort8*)(Vbase + (size_t)vr1 * SEQ + kn + vc1 * 8);
        }
        if (k0 > q0w + 31) continue;

        f32x16 s0 = {}, s1 = {};
        __builtin_amdgcn_s_setprio(1);
#pragma unroll
        for (int dc = 0; dc < 6; ++dc) {
            const int co = (dc * 16 + h * 8) ^ swz;
            bf16x8 ka = *(const bf16x8*)(Klds + l31 * 128 + co);
            bf16x8 kb2 = *(const bf16x8*)(Klds + (32 + l31) * 128 + co);
            s0 = __builtin_amdgcn_mfma_f32_32x32x16_bf16(ka, qf[dc], s0, 0, 0, 0);
            s1 = __builtin_amdgcn_mfma_f32_32x32x16_bf16(kb2, qf[dc], s1, 0, 0, 0);
        }
        __builtin_amdgcn_s_setprio(0);

        const int qg = q0w + l31;
        if (k0 + 63 > q0w) {
#pragma unroll
            for (int r = 0; r < 16; ++r) {
                const int kg = k0 + (r & 3) + 8 * (r >> 2) + 4 * h;
                if (kg > qg) s0[r] = -2e30f;
                if (kg + 32 > qg) s1[r] = -2e30f;
            }
        }
        float pmax = s0[0];
#pragma unroll
        for (int r = 1; r < 16; ++r) pmax = fmaxf(pmax, s0[r]);
#pragma unroll
        for (int r = 0; r < 16; ++r) pmax = fmaxf(pmax, s1[r]);
        pmax = fmaxf(pmax, __shfl_xor(pmax, 32, 64));
        if (!__all(pmax <= mrow + 8.0f)) {
            float mnew = fmaxf(mrow, pmax);
            float scl = __expf(mrow - mnew);
            mrow = mnew;
            lrow *= scl;
#pragma unroll
            for (int r = 0; r < 16; ++r) {
                float sq = __shfl(scl, (r & 3) + 8 * (r >> 2) + 4 * h, 64);
                acc0[r] *= sq; acc1[r] *= sq; acc2[r] *= sq;
            }
        }
        float ps = 0.f;
#pragma unroll
        for (int r = 0; r < 16; ++r) { s0[r] = __expf(s0[r] - mrow); ps += s0[r]; }
#pragma unroll
        for (int r = 0; r < 16; ++r) { s1[r] = __expf(s1[r] - mrow); ps += s1[r]; }
        lrow += ps + __shfl_xor(ps, 32, 64);
        i32x4 af[2][2];
#pragma unroll
        for (int ks = 0; ks < 2; ++ks) {
            const f32x16& sv = ks ? s1 : s0;
            int pk0[2], pk1[2], pk2[2], pk3[2];
#pragma unroll
            for (int i = 0; i < 2; ++i) {
                pk0[i] = cvt_pk_bf16(sv[2 * i], sv[2 * i + 1]);
                pk1[i] = cvt_pk_bf16(sv[4 + 2 * i], sv[5 + 2 * i]);
                pk2[i] = cvt_pk_bf16(sv[8 + 2 * i], sv[9 + 2 * i]);
                pk3[i] = cvt_pk_bf16(sv[12 + 2 * i], sv[13 + 2 * i]);
            }
#pragma unroll
            for (int i = 0; i < 2; ++i) {
                const int o0 = __shfl_xor(pk0[i], 32, 64);
                const int o1 = __shfl_xor(pk1[i], 32, 64);
                af[ks][0][i]     = h ? o1     : pk0[i];
                af[ks][0][2 + i] = h ? pk1[i] : o0;
                const int o2 = __shfl_xor(pk2[i], 32, 64);
                const int o3 = __shfl_xor(pk3[i], 32, 64);
                af[ks][1][i]     = h ? o3     : pk2[i];
                af[ks][1][2 + i] = h ? pk3[i] : o2;
            }
        }
        __builtin_amdgcn_s_setprio(1);
#pragma unroll
        for (int ds = 0; ds < 3; ++ds) {
            f32x16& ac = ds == 0 ? acc0 : (ds == 1 ? acc1 : acc2);
            const int vrow = (ds * 32 + l31) * 64;
#pragma unroll
            for (int ks = 0; ks < 2; ++ks)
#pragma unroll
                for (int kh = 0; kh < 2; ++kh) {
                    bf16x8 vb = *(const bf16x8*)(Vlds + vrow + ((ks * 32 + kh * 16 + h * 8) ^ swz));
                    bf16x8 pa = __builtin_bit_cast(bf16x8, af[ks][kh]);
                    ac = __builtin_amdgcn_mfma_f32_32x32x16_bf16(pa, vb, ac, 0, 0, 0);
                }
        }
        __builtin_amdgcn_s_setprio(0);
    }

    const int hh = bh & 31, b = bh >> 5;
    const float linv = 1.0f / lrow;
#pragma unroll
    for (int r = 0; r < 16; ++r) {
        const int ql = (r & 3) + 8 * (r >> 2) + 4 * h;
        const float lv = __shfl(linv, ql, 64);
        const int row = b * SEQ + q0b + wid * 32 + ql;
        unsigned short* orow = attn + (size_t)row * HIDDEN + hh * HDIM;
        orow[l31] = f2bf(acc0[r] * lv);
        orow[32 + l31] = f2bf(acc1[r] * lv);
        if (l31 < 16) orow[64 + l31] = f2bf(acc2[r] * lv);
    }
}

extern "C" void kernel_launch(void* const* d_in, const int* in_sizes, int n_in,
                              void* d_out, int out_size, void* d_ws, size_t ws_size,
                              hipStream_t stream) {
    const int* pos = (const int*)d_in[0];
    const float* hid = (const float*)d_in[1];
    const float* Wqkv = (const float*)d_in[2];
    const float* bqkv = (const float*)d_in[3];
    const float* Wd = (const float*)d_in[4];
    const float* bd = (const float*)d_in[5];
    float* out = (float*)d_out;
    char* ws = (char*)d_ws;

    unsigned short* WqkvT = (unsigned short*)(ws);                // 39,321,600 B
    unsigned short* WdT   = (unsigned short*)(ws + 39321600);     // 13,107,200 B
    unsigned short* Xbf   = (unsigned short*)(ws + 52428800);     // 20,971,520 B
    unsigned short* qkv   = (unsigned short*)(ws + 73400320);     // 62,914,560 B
    unsigned short* Qbuf  = (unsigned short*)(ws + 136314880);    // 25,165,824 B
    unsigned short* Kbuf  = (unsigned short*)(ws + 161480704);    // 25,165,824 B
    unsigned short* Vt    = (unsigned short*)(ws + 186646528);    // 20,971,520 B
    unsigned short* attnb = Xbf;  // Xbf dead after gemm1; reuse for attention output

    cvt_kernel<<<(M_TOK * HIDDEN / 8 + 255) / 256, 256, 0, stream>>>(hid, Xbf, M_TOK * HIDDEN / 8);
    transpose_kernel<<<dim3(N_QKV / 64, HIDDEN / 64), 256, 0, stream>>>(Wqkv, WqkvT, HIDDEN, N_QKV);
    transpose_kernel<<<dim3(HIDDEN / 64, HIDDEN / 64), 256, 0, stream>>>(Wd, WdT, HIDDEN, HIDDEN);
    gemm256<1><<<(M_TOK / 256) * (N_QKV / 256), 512, 0, stream>>>(Xbf, WqkvT, bqkv, qkv,
                                                                  M_TOK, N_QKV, HIDDEN);
    pack_rope_kernel<<<(64 * SEQ) / 256, 256, 0, stream>>>(qkv, pos, Qbuf, Kbuf, Vt);
    flash_kernel<<<dim3(64, 8), 512, 0, stream>>>(Qbuf, Kbuf, Vt, attnb);
    gemm256<0><<<(M_TOK / 256) * (HIDDEN / 256), 512, 0, stream>>>(attnb, WdT, bd, out,
                                                                   M_TOK, HIDDEN, HIDDEN);
}